// Round 12
// baseline (1372.258 us; speedup 1.0000x reference)
//
#include <hip/hip_runtime.h>
#include <hip/hip_bf16.h>
#include <cstdint>

#define NB 8
#define NP 16384
#define NG 512
#define NS 32
#define TDM 384
#define BGT (NB*NG)        // 4096 groups total
#define NR (BGT*NS)        // 131072 rows
#define C1 128
#define C2 256
#define C3 512

typedef __attribute__((ext_vector_type(8))) short bfrag;   // 8 bf16
typedef __attribute__((ext_vector_type(4))) float facc;    // 4 f32
typedef __attribute__((ext_vector_type(2))) float f32x2;

__device__ __forceinline__ ushort f2bf(float f) {
  uint32_t u = __float_as_uint(f);
  uint32_t r = (u + 0x7FFFu + ((u >> 16) & 1u)) >> 16;  // RNE
  return (ushort)r;
}
__device__ __forceinline__ float bf2f(ushort h) {
  return __uint_as_float(((uint32_t)h) << 16);
}

// async global->LDS, 16B per lane. LDS dst must be linear in lane order
// (wave-uniform base + lane*16); swizzled layouts are achieved by
// inverse-swizzling the per-lane GLOBAL source (m104/m173 pattern).
__device__ __forceinline__ void gld_lds16(const void* g, void* l) {
  __builtin_amdgcn_global_load_lds(
      (const __attribute__((address_space(1))) void*)g,
      (__attribute__((address_space(3))) void*)l, 16, 0, 0);
}

// ---------------- ws layout (bytes) ----------------
#define OFF_CIDX   0u
#define OFF_CENT   16384u
#define OFF_GROUP  65536u      // 131072*3*4 = 1572864
#define OFF_XPART  1638400u    // 4096*9*4   = 147456
#define OFF_BN1    1785856u    // 128*2*4
#define OFF_BN3    1786880u    // 512*2*4
#define OFF_W2B    1790976u    // 32768*2
#define OFF_W3BB   1856512u    // 131072*2
#define OFF_W4B    2118656u    // 196608*2
#define OFF_FG     2511872u    // 4096*256*4 = 4194304
#define OFF_FGP    6706176u    // 4096*512*4 = 8388608
#define OFF_PART   15094784u   // 1024*1024*4 = 4194304 (also fps m-state: 512KB, dead until l34<0>)
#define OFF_F2     19289088u   // 131072*256*2 = 67108864  -> end 86397952

// ---------------- FPS (4 phases of 128 iters) + prep folded into phase 0 ----------------
// R3-proven algorithm (bit-exact): pack (mind_bits, ~idx) into a positive
// finite double; u64 order == double order -> argmax + first-index tie-break
// is a pure v_max_f64 reduction. Phase p runs iters [max(1,p*128),(p+1)*128);
// per-thread mind state saved/restored via mstate (bit-exact continuation).
// Phase 0 additionally carries 712 prep blocks (weight bf16 convert + mask)
// that run on the otherwise-idle CUs.
template <int PHASE>
__global__ __launch_bounds__(512, 2) void k_fps(const float* __restrict__ pts,
                                                int* __restrict__ cidx,
                                                float* __restrict__ centers,
                                                float* __restrict__ outc,
                                                float* __restrict__ mstate,
                                                const float* __restrict__ w2,
                                                const float* __restrict__ w3,
                                                const float* __restrict__ w4,
                                                ushort* __restrict__ w2b,
                                                ushort* __restrict__ w3bb,
                                                ushort* __restrict__ w4b,
                                                float* __restrict__ mask) {
#pragma clang fp contract(off)
  const int t = threadIdx.x;
  if (PHASE == 0 && blockIdx.x >= NB) {      // prep blocks (idle CUs)
    int i = (blockIdx.x - NB) * 512 + t;
    if (i < 32768) {
      int r = i >> 7, c = i & 127;
      w2b[i] = f2bf(w2[r * 128 + c]);
    } else if (i < 163840) {
      int j = i - 32768; int r = j >> 8, c = j & 255;
      w3bb[j] = f2bf(w3[(size_t)r * 512 + 256 + c]);
    } else if (i < 360448) {
      int j = i - 163840; int r = j >> 9, c = j & 511;
      w4b[j] = f2bf(w4[(size_t)r * 512 + c]);
    } else if (i < 364544) {
      mask[i - 360448] = 1.0f;
    }
    return;
  }
  const int b = blockIdx.x;
  const float* P = pts + (size_t)b * NP * 3;
  f32x2 px[16], py[16], pz[16], m[16];
#pragma unroll
  for (int k = 0; k < 16; k++) {
    int p0 = (2 * k) * 512 + t;
    int p1 = p0 + 512;
    px[k] = (f32x2){P[p0 * 3 + 0], P[p1 * 3 + 0]};
    py[k] = (f32x2){P[p0 * 3 + 1], P[p1 * 3 + 1]};
    pz[k] = (f32x2){P[p0 * 3 + 2], P[p1 * 3 + 2]};
    if (PHASE == 0) {
      m[k] = (f32x2){1e10f, 1e10f};
    } else {
      m[k].x = mstate[(size_t)(b * 32 + 2 * k) * 512 + t];
      m[k].y = mstate[(size_t)(b * 32 + 2 * k + 1) * 512 + t];
    }
  }
  __shared__ double kb[2][8];
  float cx, cy, cz;
  if (PHASE == 0) {
    cx = P[0]; cy = P[1]; cz = P[2];
    if (t == 0) {
      cidx[b * NG] = 0;
      size_t o = (size_t)b * NG * 3;
      centers[o] = cx; centers[o + 1] = cy; centers[o + 2] = cz;
      outc[o] = cx; outc[o + 1] = cy; outc[o + 2] = cz;
    }
  } else {
    // last center written by previous phase (i = PHASE*128 - 1)
    size_t o = ((size_t)b * NG + (PHASE * 128 - 1)) * 3;
    cx = centers[o]; cy = centers[o + 1]; cz = centers[o + 2];
  }
  const unsigned nt = ~(unsigned)t;
  const int i_beg = (PHASE == 0) ? 1 : PHASE * 128;
  const int i_end = (PHASE + 1) * 128;
  for (int i = i_beg; i < i_end; i++) {
    const int par = i & 1;
    const f32x2 ccx = (f32x2){cx, cx};
    const f32x2 ccy = (f32x2){cy, cy};
    const f32x2 ccz = (f32x2){cz, cz};
    double A = 0.0, B = 0.0;   // 2 independent 8-deep max chains
#pragma unroll
    for (int k = 0; k < 16; k++) {
      // exact reference arithmetic: sub, mul, (x2+y2)+z2, no fma (contract off)
      f32x2 dx = px[k] - ccx;
      f32x2 dy = py[k] - ccy;
      f32x2 dz = pz[k] - ccz;
      f32x2 d = (dx * dx + dy * dy) + dz * dz;
      f32x2 mm = __builtin_elementwise_min(m[k], d);
      m[k] = mm;
      unsigned lo0 = nt - (unsigned)(2 * k) * 512u;       // == ~(p0)
      unsigned lo1 = nt - (unsigned)(2 * k + 1) * 512u;   // == ~(p1)
      double k0 = __longlong_as_double(((unsigned long long)__float_as_uint(mm.x) << 32) | lo0);
      double k1 = __longlong_as_double(((unsigned long long)__float_as_uint(mm.y) << 32) | lo1);
      A = fmax(A, k0);
      B = fmax(B, k1);
    }
    double best = fmax(A, B);
#pragma unroll
    for (int off = 1; off < 64; off <<= 1)
      best = fmax(best, __shfl_xor(best, off));
    if ((t & 63) == 0) kb[par][t >> 6] = best;
    __syncthreads();
    // every thread reduces the 8 wave keys (broadcast LDS reads)
    double v0 = fmax(kb[par][0], kb[par][1]);
    double v1 = fmax(kb[par][2], kb[par][3]);
    double v2 = fmax(kb[par][4], kb[par][5]);
    double v3 = fmax(kb[par][6], kb[par][7]);
    const double g = fmax(fmax(v0, v1), fmax(v2, v3));
    const int gidx = (int)(~(unsigned)__double_as_longlong(g));
    // all lanes load winner coords (uniform address -> one fetch + broadcast)
    const float* q = P + (size_t)gidx * 3;
    cx = q[0]; cy = q[1]; cz = q[2];
    if (t == 0) {
      cidx[b * NG + i] = gidx;
      size_t o = ((size_t)b * NG + i) * 3;
      centers[o] = cx; centers[o + 1] = cy; centers[o + 2] = cz;
      outc[o] = cx; outc[o + 1] = cy; outc[o + 2] = cz;
    }
  }
  if (PHASE < 3) {
#pragma unroll
    for (int k = 0; k < 16; k++) {
      mstate[(size_t)(b * 32 + 2 * k) * 512 + t] = m[k].x;
      mstate[(size_t)(b * 32 + 2 * k + 1) * 512 + t] = m[k].y;
    }
  }
}

// ---------------- KNN + group + x-stat partials ----------------
// d[32] register-resident; single-pass rank-select over boundary-bin
// candidates (exact same selected SET as iterative lex-min extraction).
// LDS: sd[16384] f32 @0 | h1[256] @65536 | h2[256] @66560 | cand[1024] @67584
//      sel[32] @71680 | selc[96] @71808 | redv[8] @72192 | redi[8] @72224 | cnts[8] @72256
#define KNN_LDS 72704
__global__ __launch_bounds__(512) void k_knn(const float* __restrict__ pts,
                                             const float* __restrict__ centers,
                                             float* __restrict__ group,
                                             float* __restrict__ xpart) {
  extern __shared__ char sm[];
  float* sd = (float*)sm;
  uint32_t* h1 = (uint32_t*)(sm + 65536);
  uint32_t* h2 = (uint32_t*)(sm + 66560);
  int* cand = (int*)(sm + 67584);
  int* sel = (int*)(sm + 71680);
  float* selc = (float*)(sm + 71808);
  float* redv = (float*)(sm + 72192);
  int* redi = (int*)(sm + 72224);
  int* cnts = (int*)(sm + 72256);
  const int t = threadIdx.x;
  const int bg = blockIdx.x;
  const int b = bg >> 9;
  const float* P = pts + (size_t)b * NP * 3;
  const float cx = centers[bg * 3], cy = centers[bg * 3 + 1], cz = centers[bg * 3 + 2];
  float dl[32];
#pragma unroll
  for (int rr = 0; rr < NP / 512; rr++) {
    int p = rr * 512 + t;
    float dx = __fsub_rn(P[p * 3], cx);
    float dy = __fsub_rn(P[p * 3 + 1], cy);
    float dz = __fsub_rn(P[p * 3 + 2], cz);
    float d = __fadd_rn(__fadd_rn(__fmul_rn(dx, dx), __fmul_rn(dy, dy)), __fmul_rn(dz, dz));
    dl[rr] = d;
    sd[p] = d;
  }
  if (t < 256) { h1[t] = 0; h2[t] = 0; }
  if (t < 8) cnts[t] = 0;
  __syncthreads();
#pragma unroll
  for (int rr = 0; rr < NP / 512; rr++)
    atomicAdd(&h1[__float_as_uint(dl[rr]) >> 23], 1u);
  __syncthreads();
  if (t == 0) {
    int cum = 0, e = 0;
    for (; e < 256; e++) { int c2 = cum + (int)h1[e]; if (c2 >= NS) break; cum = c2; }
    cnts[2] = e; cnts[3] = cum;
  }
  __syncthreads();
  const uint32_t e1 = (uint32_t)cnts[2];
#pragma unroll
  for (int rr = 0; rr < NP / 512; rr++) {
    uint32_t bits = __float_as_uint(dl[rr]);
    if ((bits >> 23) == e1) atomicAdd(&h2[(bits >> 15) & 255u], 1u);
  }
  __syncthreads();
  if (t == 0) {
    int cum = cnts[3], mm = 0;
    for (; mm < 256; mm++) { int c2 = cum + (int)h2[mm]; if (c2 >= NS) break; cum = c2; }
    cnts[4] = mm; cnts[5] = cum;
  }
  __syncthreads();
  const uint32_t keystar = (e1 << 8) | (uint32_t)cnts[4];
  const int lt = cnts[5];            // strictly-below count, < 32
#pragma unroll
  for (int rr = 0; rr < NP / 512; rr++) {
    int p = rr * 512 + t;
    uint32_t key = __float_as_uint(dl[rr]) >> 15;
    if (key < keystar) { int pos = atomicAdd(&cnts[0], 1); sel[pos] = p; }
    else if (key == keystar) { int pos = atomicAdd(&cnts[1], 1); if (pos < 1024) cand[pos] = p; }
  }
  __syncthreads();
  const int neq = cnts[1];
  if (neq <= 1024) {
    // rank-select: one pass, one barrier (typ. neq << 100)
    const int need = NS - lt;
    for (int e = t; e < neq; e += 512) {
      int p = cand[e];
      float v = sd[p];
      int rank = 0;
      for (int q = 0; q < neq; q++) {
        int pq = cand[q];                 // broadcast LDS reads
        float vq = sd[pq];
        rank += (vq < v || (vq == v && pq < p)) ? 1 : 0;
      }
      if (rank < need) sel[lt + rank] = p;
    }
    __syncthreads();
  } else {
    // overflow fallback (rare): iterative lex-min extraction over all points
    for (int j = 0; j < NS; j++) {
      float bvv = 3.4e38f; int bii = 0x7FFFFFFF;
      for (int e = t; e < NP; e += 512) {
        float v = sd[e];
        if (v < bvv || (v == bvv && e < bii)) { bvv = v; bii = e; }
      }
#pragma unroll
      for (int off = 32; off >= 1; off >>= 1) {
        float ov = __shfl_xor(bvv, off);
        int   oi = __shfl_xor(bii, off);
        if (ov < bvv || (ov == bvv && oi < bii)) { bvv = ov; bii = oi; }
      }
      if ((t & 63) == 0) { redv[t >> 6] = bvv; redi[t >> 6] = bii; }
      __syncthreads();
      if (t == 0) {
        float fv = redv[0]; int fi = redi[0];
        for (int q = 1; q < 8; q++)
          if (redv[q] < fv || (redv[q] == fv && redi[q] < fi)) { fv = redv[q]; fi = redi[q]; }
        sel[j] = fi;
        sd[fi] = 3.4e38f;
      }
      __syncthreads();
    }
  }
  if (t < NS) {
    int p = sel[t];
    float gx = __fsub_rn(P[p * 3], cx);
    float gy = __fsub_rn(P[p * 3 + 1], cy);
    float gz = __fsub_rn(P[p * 3 + 2], cz);
    size_t row = ((size_t)bg * NS + t) * 3;
    group[row] = gx; group[row + 1] = gy; group[row + 2] = gz;
    selc[t * 3] = gx; selc[t * 3 + 1] = gy; selc[t * 3 + 2] = gz;
  }
  __syncthreads();
  if (t == 0) {
    float s0=0,s1=0,s2=0,s3=0,s4=0,s5=0,s6=0,s7=0,s8=0;
    for (int r = 0; r < NS; r++) {
      float x = selc[r * 3], y = selc[r * 3 + 1], z = selc[r * 3 + 2];
      s0 += x; s1 += y; s2 += z;
      s3 += x * x; s4 += y * y; s5 += z * z;
      s6 += x * y; s7 += x * z; s8 += y * z;
    }
    float* xp = xpart + (size_t)bg * 9;
    xp[0]=s0; xp[1]=s1; xp[2]=s2; xp[3]=s3; xp[4]=s4; xp[5]=s5; xp[6]=s6; xp[7]=s7; xp[8]=s8;
  }
}

// ---------------- BN1 from analytic moments ----------------
__global__ __launch_bounds__(256) void k_bn1(const float* __restrict__ xpart,
                                             const float* __restrict__ w1,
                                             const float* __restrict__ g1,
                                             const float* __restrict__ be1,
                                             float* __restrict__ bn1) {
  __shared__ float wsum[4][9];
  __shared__ float S[9];
  const int t = threadIdx.x;
  float s[9];
#pragma unroll
  for (int j = 0; j < 9; j++) s[j] = 0.f;
  for (int i = t; i < BGT; i += 256) {
    const float* xp = xpart + (size_t)i * 9;
#pragma unroll
    for (int j = 0; j < 9; j++) s[j] += xp[j];
  }
#pragma unroll
  for (int off = 32; off >= 1; off >>= 1)
#pragma unroll
    for (int j = 0; j < 9; j++) s[j] += __shfl_xor(s[j], off);
  if ((t & 63) == 0)
#pragma unroll
    for (int j = 0; j < 9; j++) wsum[t >> 6][j] = s[j];
  __syncthreads();
  if (t == 0)
#pragma unroll
    for (int j = 0; j < 9; j++) S[j] = wsum[0][j] + wsum[1][j] + wsum[2][j] + wsum[3][j];
  __syncthreads();
  if (t < C1) {
    const float rn = 1.0f / (float)NR;
    float ex = S[0]*rn, ey = S[1]*rn, ez = S[2]*rn;
    float exx = S[3]*rn, eyy = S[4]*rn, ezz = S[5]*rn;
    float exy = S[6]*rn, exz = S[7]*rn, eyz = S[8]*rn;
    float a = w1[t*3], b = w1[t*3+1], c = w1[t*3+2];
    float mean = a*ex + b*ey + c*ez;
    float e2 = a*a*exx + b*b*eyy + c*c*ezz + 2.f*(a*b*exy + a*c*exz + b*c*eyz);
    float var = e2 - mean*mean;
    float sc = g1[t] / sqrtf(var + 1e-5f);
    bn1[t*2] = sc;
    bn1[t*2+1] = be1[t] - mean*sc;
  }
}

// ---------------- layer1+2 fused GEMM + fg ----------------
// LDS: xr @0 | a1s1 @1536 | f1A @4096 (32KB) | w2B @36864 (64KB) | f2s @4096 (64KB, reuse)
#define L12_LDS 102400
__global__ __launch_bounds__(512) void k_l12(const float* __restrict__ group,
                                             const float* __restrict__ w1,
                                             const float* __restrict__ bn1,
                                             const ushort* __restrict__ w2b,
                                             const float* __restrict__ b2,
                                             ushort* __restrict__ f2,
                                             float* __restrict__ fg) {
  extern __shared__ char sm[];
  float* xr = (float*)sm;
  float* a1s1 = (float*)(sm + 1536);
  char* f1A = sm + 4096;
  char* w2B = sm + 36864;
  char* f2s = sm + 4096;
  const int t = threadIdx.x;
  const int mb = blockIdx.x;
  const size_t R0 = (size_t)mb * 128;
  if (t < 384) xr[t] = group[R0 * 3 + t];
  if (t < 256) a1s1[t] = bn1[t];
  for (int u = t; u < 4096; u += 512) {      // w2 [256][128] bf16: async, linear LDS,
    int row = u >> 4, c = u & 15;            // inverse-swizzled global src
    gld_lds16((const int4*)w2b + (row * 16 + (c ^ (row & 7))), w2B + u * 16);
  }
  __syncthreads();
  {
    const int c = t & 127;
    const int rb = t >> 7;
    const float wa = w1[c*3], wb = w1[c*3+1], wc = w1[c*3+2];
    const float a1 = a1s1[c*2], s1 = a1s1[c*2+1];
#pragma unroll 4
    for (int i = 0; i < 32; i++) {
      int r = rb * 32 + i;
      float f = xr[r*3] * wa + xr[r*3+1] * wb + xr[r*3+2] * wc;
      float h = fmaxf(fmaf(f, a1, s1), 0.0f);
      *(ushort*)(f1A + r * 256 + ((c * 2) ^ ((r & 7) << 4))) = f2bf(h);
    }
  }
  __syncthreads();
  const int l = t & 63, w = t >> 6;
  const int wm = w >> 2, wn = w & 3;   // 2 x 4 waves, wave tile 64x64
  const int lr = l & 15, lh = l >> 4;
  facc acc[4][4];
#pragma unroll
  for (int tm = 0; tm < 4; tm++)
#pragma unroll
    for (int tn = 0; tn < 4; tn++) acc[tm][tn] = (facc)0.0f;
#pragma unroll
  for (int ks = 0; ks < 4; ks++) {
    const int kb = (ks * 32 + lh * 8) * 2;
    bfrag af[4], bf[4];
#pragma unroll
    for (int tm = 0; tm < 4; tm++) {
      int row = wm * 64 + tm * 16 + lr;
      af[tm] = *(const bfrag*)(f1A + row * 256 + (kb ^ ((row & 7) << 4)));
    }
#pragma unroll
    for (int tn = 0; tn < 4; tn++) {
      int rn = wn * 64 + tn * 16 + lr;
      bf[tn] = *(const bfrag*)(w2B + rn * 256 + (kb ^ ((rn & 7) << 4)));
    }
#pragma unroll
    for (int tm = 0; tm < 4; tm++)
#pragma unroll
      for (int tn = 0; tn < 4; tn++)
        acc[tm][tn] = __builtin_amdgcn_mfma_f32_16x16x32_bf16(af[tm], bf[tn], acc[tm][tn], 0, 0, 0);
  }
  __syncthreads();   // before reusing region as f2s
#pragma unroll
  for (int tn = 0; tn < 4; tn++) {
    int col = wn * 64 + tn * 16 + lr;
    float bb = b2[col];
#pragma unroll
    for (int tm = 0; tm < 4; tm++)
#pragma unroll
      for (int r = 0; r < 4; r++) {
        int row = wm * 64 + tm * 16 + lh * 4 + r;
        *(ushort*)(f2s + row * 512 + ((col * 2) ^ ((row & 7) << 4))) = f2bf(acc[tm][tn][r] + bb);
      }
  }
  __syncthreads();
  for (int u = t; u < 4096; u += 512) {      // f2 tile -> global, [128][256] bf16
    int row = u >> 5, cu = u & 31;
    int4 v = *(const int4*)(f2s + row * 512 + ((cu * 16) ^ ((row & 7) << 4)));
    ((int4*)(f2 + R0 * 256))[u] = v;
  }
  for (int task = t; task < 1024; task += 512) {
    int g = task >> 8, c = task & 255;
    float mx = -3.4e38f;
#pragma unroll 8
    for (int r = 0; r < 32; r++) {
      int row = g * 32 + r;
      mx = fmaxf(mx, bf2f(*(const ushort*)(f2s + row * 512 + ((c * 2) ^ ((row & 7) << 4)))));
    }
    fg[(size_t)(mb * 4 + g) * 256 + c] = mx;
  }
}

// ---------------- fgpart = fg @ w3[:, :256]^T (f32) ----------------
__global__ __launch_bounds__(256) void k_fgpart(const float* __restrict__ fg,
                                                const float* __restrict__ w3,
                                                float* __restrict__ fgpart) {
  __shared__ float fgs[16 * 256];
  const int t = threadIdx.x;
  const int g0 = blockIdx.x * 16;
  for (int i = t; i < 4096; i += 256) fgs[i] = fg[(size_t)g0 * 256 + i];
  __syncthreads();
  for (int half = 0; half < 2; half++) {
    int n = half * 256 + t;
    const float* wr = w3 + (size_t)n * 512;
    float acc[16];
#pragma unroll
    for (int r = 0; r < 16; r++) acc[r] = 0.f;
    for (int k = 0; k < 256; k++) {
      float wv = wr[k];
#pragma unroll
      for (int r = 0; r < 16; r++) acc[r] = fmaf(fgs[r * 256 + k], wv, acc[r]);
    }
#pragma unroll
    for (int r = 0; r < 16; r++) fgpart[(size_t)(g0 + r) * 512 + n] = acc[r];
  }
}

// ---------------- layer3 (+stats) / layer3+4+max (OUT=1) ----------------
// LDS: A @0 (64KB) | B @65536 (64KB) | Hl/stats @131072
#define L34S_LDS 133120
#define L34O_LDS 163840
template <int OUT>
__global__ __launch_bounds__(512) void k_l34(const ushort* __restrict__ f2,
                                             const ushort* __restrict__ w3bb,
                                             const ushort* __restrict__ w4b,
                                             const float* __restrict__ fgpart,
                                             const float* __restrict__ bn3,
                                             const float* __restrict__ b4,
                                             float* __restrict__ partials,
                                             float* __restrict__ tokens) {
  extern __shared__ char sm[];
  char* Al = sm;
  char* Bl = sm + 65536;
  char* Hl = sm + 131072;
  float* st = (float*)(sm + 131072);
  const int t = threadIdx.x;
  const int mb = blockIdx.x;
  const size_t R0 = (size_t)mb * 128;
  const int g0 = mb * 4;
  const int l = t & 63, w = t >> 6;
  const int wm = w >> 2, wn = w & 3;   // 2 x 4 waves
  const int lr = l & 15, lh = l >> 4;
  for (int u = t; u < 4096; u += 512) {      // A: f2 tile, async linear-LDS
    int row = u >> 5, c = u & 31;
    gld_lds16((const int4*)(f2 + R0 * 256) + (row * 32 + (c ^ (row & 7))), Al + u * 16);
  }
  facc tacc[4][6];
  if (OUT) {
#pragma unroll
    for (int tm = 0; tm < 4; tm++)
#pragma unroll
      for (int tn = 0; tn < 6; tn++) tacc[tm][tn] = (facc)0.0f;
  }
  for (int kc = 0; kc < 4; kc++) {
    for (int u = t; u < 4096; u += 512) {    // B: w3bb rows [kc*128,+128), async
      int row = u >> 5, c = u & 31;
      gld_lds16((const int4*)(w3bb + (size_t)kc * 128 * 256) + (row * 32 + (c ^ (row & 7))),
                Bl + u * 16);
    }
    __syncthreads();
    facc acc[4][2];
#pragma unroll
    for (int tm = 0; tm < 4; tm++) { acc[tm][0] = (facc)0.0f; acc[tm][1] = (facc)0.0f; }
#pragma unroll
    for (int ks = 0; ks < 8; ks++) {
      const int kb = (ks * 32 + lh * 8) * 2;
      bfrag af[4], bf[2];
#pragma unroll
      for (int tm = 0; tm < 4; tm++) {
        int row = wm * 64 + tm * 16 + lr;
        af[tm] = *(const bfrag*)(Al + row * 512 + (kb ^ ((row & 7) << 4)));
      }
#pragma unroll
      for (int tn = 0; tn < 2; tn++) {
        int rn = wn * 32 + tn * 16 + lr;
        bf[tn] = *(const bfrag*)(Bl + rn * 512 + (kb ^ ((rn & 7) << 4)));
      }
#pragma unroll
      for (int tm = 0; tm < 4; tm++)
#pragma unroll
        for (int tn = 0; tn < 2; tn++)
          acc[tm][tn] = __builtin_amdgcn_mfma_f32_16x16x32_bf16(af[tm], bf[tn], acc[tm][tn], 0, 0, 0);
    }
    float fgp0[2], fgp1[2], a3c[2], s3c[2];
#pragma unroll
    for (int tn = 0; tn < 2; tn++) {
      int col = kc * 128 + wn * 32 + tn * 16 + lr;
      fgp0[tn] = fgpart[(size_t)(g0 + wm * 2) * 512 + col];
      fgp1[tn] = fgpart[(size_t)(g0 + wm * 2 + 1) * 512 + col];
      if (OUT) { a3c[tn] = bn3[col * 2]; s3c[tn] = bn3[col * 2 + 1]; }
    }
    if (OUT == 0) {
      float s1v[2] = {0.f, 0.f}, s2v[2] = {0.f, 0.f};
#pragma unroll
      for (int tm = 0; tm < 4; tm++)
#pragma unroll
        for (int tn = 0; tn < 2; tn++)
#pragma unroll
          for (int r = 0; r < 4; r++) {
            float f3 = acc[tm][tn][r] + (tm < 2 ? fgp0[tn] : fgp1[tn]);
            s1v[tn] += f3; s2v[tn] += f3 * f3;
          }
#pragma unroll
      for (int tn = 0; tn < 2; tn++) {
        s1v[tn] += __shfl_xor(s1v[tn], 16); s1v[tn] += __shfl_xor(s1v[tn], 32);
        s2v[tn] += __shfl_xor(s2v[tn], 16); s2v[tn] += __shfl_xor(s2v[tn], 32);
      }
      if (l < 16) {
#pragma unroll
        for (int tn = 0; tn < 2; tn++) {
          int cl = wn * 32 + tn * 16 + lr;
          st[(wm * 128 + cl) * 2 + 0] = s1v[tn];
          st[(wm * 128 + cl) * 2 + 1] = s2v[tn];
        }
      }
      __syncthreads();
      if (t < 256) {
        int cl = t & 127, s = t >> 7;
        float tot = st[(0 * 128 + cl) * 2 + s] + st[(1 * 128 + cl) * 2 + s];
        partials[(size_t)mb * 1024 + (size_t)(kc * 128 + cl) * 2 + s] = tot;
      }
      __syncthreads();
    } else {
#pragma unroll
      for (int tm = 0; tm < 4; tm++)
#pragma unroll
        for (int tn = 0; tn < 2; tn++)
#pragma unroll
          for (int r = 0; r < 4; r++) {
            int row = wm * 64 + tm * 16 + lh * 4 + r;
            int cl = wn * 32 + tn * 16 + lr;
            float f3 = acc[tm][tn][r] + (tm < 2 ? fgp0[tn] : fgp1[tn]);
            float hv = fmaxf(fmaf(f3, a3c[tn], s3c[tn]), 0.0f);
            *(ushort*)(Hl + row * 256 + ((cl * 2) ^ ((row & 7) << 4))) = f2bf(hv);
          }
      __syncthreads();  // h ready; B free
#pragma unroll
      for (int p = 0; p < 2; p++) {
        for (int u = t; u < 3072; u += 512) {   // w4 piece [384][64] bf16, async
          int row = u >> 3, c = u & 7;
          gld_lds16((const int4*)(w4b + (size_t)row * 512 + kc * 128 + p * 64) + (c ^ (row & 7)),
                    Bl + u * 16);
        }
        __syncthreads();
#pragma unroll
        for (int ks = 0; ks < 2; ks++) {
          const int kbh = (p * 64 + ks * 32 + lh * 8) * 2;
          const int kbb = (ks * 32 + lh * 8) * 2;
          bfrag af[4], bf[6];
#pragma unroll
          for (int tm = 0; tm < 4; tm++) {
            int row = wm * 64 + tm * 16 + lr;
            af[tm] = *(const bfrag*)(Hl + row * 256 + (kbh ^ ((row & 7) << 4)));
          }
#pragma unroll
          for (int tn = 0; tn < 6; tn++) {
            int rn = wn * 96 + tn * 16 + lr;
            bf[tn] = *(const bfrag*)(Bl + rn * 128 + (kbb ^ ((rn & 7) << 4)));
          }
#pragma unroll
          for (int tm = 0; tm < 4; tm++)
#pragma unroll
            for (int tn = 0; tn < 6; tn++)
              tacc[tm][tn] = __builtin_amdgcn_mfma_f32_16x16x32_bf16(af[tm], bf[tn], tacc[tm][tn], 0, 0, 0);
        }
        __syncthreads();
      }
    }
  }
  if (OUT) {
#pragma unroll
    for (int tn = 0; tn < 6; tn++) {
      int col = wn * 96 + tn * 16 + lr;
      float bb = b4[col];
#pragma unroll
      for (int half = 0; half < 2; half++) {
        float mx = -3.4e38f;
#pragma unroll
        for (int tm = half * 2; tm < half * 2 + 2; tm++)
#pragma unroll
          for (int r = 0; r < 4; r++) mx = fmaxf(mx, tacc[tm][tn][r]);
        mx = fmaxf(mx, __shfl_xor(mx, 16));
        mx = fmaxf(mx, __shfl_xor(mx, 32));
        if (l < 16) tokens[(size_t)(g0 + wm * 2 + half) * TDM + col] = mx + bb;
      }
    }
  }
}

// ---------------- BN3 finalize (1024 thr: 8-way chunked sum + LDS reduce) ----------------
__global__ __launch_bounds__(1024) void k_bn3(const float* __restrict__ partials,
                                              const float* __restrict__ g3,
                                              const float* __restrict__ be3,
                                              float* __restrict__ bn3) {
  __shared__ float ls[128][8];
  const int t = threadIdx.x;
  const int slot_l = t & 127;          // slot within this block's 128
  const int chunk = t >> 7;            // 0..7
  const int slot = blockIdx.x * 128 + slot_l;
  float s = 0.f;
  for (int m = chunk * 128; m < chunk * 128 + 128; m++)
    s += partials[(size_t)m * 1024 + slot];
  ls[slot_l][chunk] = s;
  __syncthreads();
  if (t < 64) {
    int col = blockIdx.x * 64 + t;
    float s1 = 0.f, s2 = 0.f;
#pragma unroll
    for (int c = 0; c < 8; c++) { s1 += ls[2 * t][c]; s2 += ls[2 * t + 1][c]; }
    const float rn = 1.0f / (float)NR;
    float mean = s1 * rn;
    float var = s2 * rn - mean * mean;
    float a = g3[col] / sqrtf(var + 1e-5f);
    bn3[col * 2] = a;
    bn3[col * 2 + 1] = be3[col] - mean * a;
  }
}

extern "C" void kernel_launch(void* const* d_in, const int* in_sizes, int n_in,
                              void* d_out, int out_size, void* d_ws, size_t ws_size,
                              hipStream_t stream) {
  const float* points = (const float*)d_in[0];
  const float* w1 = (const float*)d_in[2];
  const float* g1 = (const float*)d_in[3];
  const float* be1 = (const float*)d_in[4];
  const float* w2 = (const float*)d_in[5];
  const float* b2 = (const float*)d_in[6];
  const float* w3 = (const float*)d_in[7];
  const float* g3 = (const float*)d_in[8];
  const float* be3 = (const float*)d_in[9];
  const float* w4 = (const float*)d_in[10];
  const float* b4 = (const float*)d_in[11];
  char* ws = (char*)d_ws;
  int* cidx = (int*)(ws + OFF_CIDX);
  float* centers = (float*)(ws + OFF_CENT);
  float* group = (float*)(ws + OFF_GROUP);
  float* xpart = (float*)(ws + OFF_XPART);
  float* bn1 = (float*)(ws + OFF_BN1);
  float* bn3 = (float*)(ws + OFF_BN3);
  ushort* w2b = (ushort*)(ws + OFF_W2B);
  ushort* w3bb = (ushort*)(ws + OFF_W3BB);
  ushort* w4b = (ushort*)(ws + OFF_W4B);
  float* fg = (float*)(ws + OFF_FG);
  float* fgpart = (float*)(ws + OFF_FGP);
  float* partials = (float*)(ws + OFF_PART);
  ushort* f2 = (ushort*)(ws + OFF_F2);
  float* out = (float*)d_out;
  float* out_centers = out + (size_t)BGT * TDM;
  float* out_mask = out_centers + (size_t)BGT * 3;

  hipFuncSetAttribute((const void*)k_knn, hipFuncAttributeMaxDynamicSharedMemorySize, KNN_LDS);
  hipFuncSetAttribute((const void*)k_l12, hipFuncAttributeMaxDynamicSharedMemorySize, L12_LDS);
  {
    auto p0 = k_l34<0>; auto p1 = k_l34<1>;
    hipFuncSetAttribute((const void*)p0, hipFuncAttributeMaxDynamicSharedMemorySize, L34S_LDS);
    hipFuncSetAttribute((const void*)p1, hipFuncAttributeMaxDynamicSharedMemorySize, L34O_LDS);
  }

  float* mstate = (float*)(ws + OFF_PART);   // dead until l34<0> writes partials

  // phase 0 carries 712 prep blocks (weight convert + mask) on idle CUs
  k_fps<0><<<NB + 712, 512, 0, stream>>>(points, cidx, centers, out_centers, mstate,
                                         w2, w3, w4, w2b, w3bb, w4b, out_mask);
  k_fps<1><<<NB, 512, 0, stream>>>(points, cidx, centers, out_centers, mstate,
                                   w2, w3, w4, w2b, w3bb, w4b, out_mask);
  k_fps<2><<<NB, 512, 0, stream>>>(points, cidx, centers, out_centers, mstate,
                                   w2, w3, w4, w2b, w3bb, w4b, out_mask);
  k_fps<3><<<NB, 512, 0, stream>>>(points, cidx, centers, out_centers, mstate,
                                   w2, w3, w4, w2b, w3bb, w4b, out_mask);
  k_knn<<<BGT, 512, KNN_LDS, stream>>>(points, centers, group, xpart);
  k_bn1<<<1, 256, 0, stream>>>(xpart, w1, g1, be1, bn1);
  k_l12<<<NR / 128, 512, L12_LDS, stream>>>(group, w1, bn1, w2b, b2, f2, fg);
  k_fgpart<<<BGT / 16, 256, 0, stream>>>(fg, w3, fgpart);
  k_l34<0><<<NR / 128, 512, L34S_LDS, stream>>>(f2, w3bb, nullptr, fgpart, nullptr, nullptr, partials, nullptr);
  k_bn3<<<8, 1024, 0, stream>>>(partials, g3, be3, bn3);
  k_l34<1><<<NR / 128, 512, L34O_LDS, stream>>>(f2, w3bb, w4b, fgpart, bn3, b4, nullptr, out);
}

// Round 13
// 1261.378 us; speedup vs baseline: 1.0879x; 1.0879x over previous
//
#include <hip/hip_runtime.h>
#include <hip/hip_bf16.h>
#include <cstdint>

#define NB 8
#define NP 16384
#define NG 512
#define NS 32
#define TDM 384
#define BGT (NB*NG)        // 4096 groups total
#define NR (BGT*NS)        // 131072 rows
#define C1 128
#define C2 256
#define C3 512

typedef __attribute__((ext_vector_type(8))) short bfrag;   // 8 bf16
typedef __attribute__((ext_vector_type(4))) float facc;    // 4 f32
typedef __attribute__((ext_vector_type(2))) float f32x2;

__device__ __forceinline__ ushort f2bf(float f) {
  uint32_t u = __float_as_uint(f);
  uint32_t r = (u + 0x7FFFu + ((u >> 16) & 1u)) >> 16;  // RNE
  return (ushort)r;
}
__device__ __forceinline__ float bf2f(ushort h) {
  return __uint_as_float(((uint32_t)h) << 16);
}

// async global->LDS, 16B per lane. LDS dst must be linear in lane order
// (wave-uniform base + lane*16); swizzled layouts are achieved by
// inverse-swizzling the per-lane GLOBAL source (m104/m173 pattern).
__device__ __forceinline__ void gld_lds16(const void* g, void* l) {
  __builtin_amdgcn_global_load_lds(
      (const __attribute__((address_space(1))) void*)g,
      (__attribute__((address_space(3))) void*)l, 16, 0, 0);
}

// ---------------- ws layout (bytes) ----------------
#define OFF_CIDX   0u
#define OFF_CENT   16384u
#define OFF_GROUP  65536u      // 131072*3*4 = 1572864
#define OFF_XPART  1638400u    // 4096*9*4   = 147456
#define OFF_BN1    1785856u    // 128*2*4
#define OFF_BN3    1786880u    // 512*2*4
#define OFF_W2B    1790976u    // 32768*2
#define OFF_W3BB   1856512u    // 131072*2
#define OFF_W4B    2118656u    // 196608*2
#define OFF_FG     2511872u    // 4096*256*4 = 4194304
#define OFF_FGP    6706176u    // 4096*512*4 = 8388608
#define OFF_PART   15094784u   // 1024*1024*4 = 4194304 (also fps m-state: 512KB, dead until l34<0>)
#define OFF_F2     19289088u   // 131072*256*2 = 67108864  -> end 86397952

// ---------------- FPS (4 phases of 128 iters) + prep folded into phase 0 ----------------
template <int PHASE>
__global__ __launch_bounds__(512, 2) void k_fps(const float* __restrict__ pts,
                                                int* __restrict__ cidx,
                                                float* __restrict__ centers,
                                                float* __restrict__ outc,
                                                float* __restrict__ mstate,
                                                const float* __restrict__ w2,
                                                const float* __restrict__ w3,
                                                const float* __restrict__ w4,
                                                ushort* __restrict__ w2b,
                                                ushort* __restrict__ w3bb,
                                                ushort* __restrict__ w4b,
                                                float* __restrict__ mask) {
#pragma clang fp contract(off)
  const int t = threadIdx.x;
  if (PHASE == 0 && blockIdx.x >= NB) {      // prep blocks (idle CUs)
    int i = (blockIdx.x - NB) * 512 + t;
    if (i < 32768) {
      int r = i >> 7, c = i & 127;
      w2b[i] = f2bf(w2[r * 128 + c]);
    } else if (i < 163840) {
      int j = i - 32768; int r = j >> 8, c = j & 255;
      w3bb[j] = f2bf(w3[(size_t)r * 512 + 256 + c]);
    } else if (i < 360448) {
      int j = i - 163840; int r = j >> 9, c = j & 511;
      w4b[j] = f2bf(w4[(size_t)r * 512 + c]);
    } else if (i < 364544) {
      mask[i - 360448] = 1.0f;
    }
    return;
  }
  const int b = blockIdx.x;
  const float* P = pts + (size_t)b * NP * 3;
  f32x2 px[16], py[16], pz[16], m[16];
#pragma unroll
  for (int k = 0; k < 16; k++) {
    int p0 = (2 * k) * 512 + t;
    int p1 = p0 + 512;
    px[k] = (f32x2){P[p0 * 3 + 0], P[p1 * 3 + 0]};
    py[k] = (f32x2){P[p0 * 3 + 1], P[p1 * 3 + 1]};
    pz[k] = (f32x2){P[p0 * 3 + 2], P[p1 * 3 + 2]};
    if (PHASE == 0) {
      m[k] = (f32x2){1e10f, 1e10f};
    } else {
      m[k].x = mstate[(size_t)(b * 32 + 2 * k) * 512 + t];
      m[k].y = mstate[(size_t)(b * 32 + 2 * k + 1) * 512 + t];
    }
  }
  __shared__ double kb[2][8];
  float cx, cy, cz;
  if (PHASE == 0) {
    cx = P[0]; cy = P[1]; cz = P[2];
    if (t == 0) {
      cidx[b * NG] = 0;
      size_t o = (size_t)b * NG * 3;
      centers[o] = cx; centers[o + 1] = cy; centers[o + 2] = cz;
      outc[o] = cx; outc[o + 1] = cy; outc[o + 2] = cz;
    }
  } else {
    size_t o = ((size_t)b * NG + (PHASE * 128 - 1)) * 3;
    cx = centers[o]; cy = centers[o + 1]; cz = centers[o + 2];
  }
  const unsigned nt = ~(unsigned)t;
  const int i_beg = (PHASE == 0) ? 1 : PHASE * 128;
  const int i_end = (PHASE + 1) * 128;
  for (int i = i_beg; i < i_end; i++) {
    const int par = i & 1;
    const f32x2 ccx = (f32x2){cx, cx};
    const f32x2 ccy = (f32x2){cy, cy};
    const f32x2 ccz = (f32x2){cz, cz};
    double A = 0.0, B = 0.0;   // 2 independent 8-deep max chains
#pragma unroll
    for (int k = 0; k < 16; k++) {
      // exact reference arithmetic: sub, mul, (x2+y2)+z2, no fma (contract off)
      f32x2 dx = px[k] - ccx;
      f32x2 dy = py[k] - ccy;
      f32x2 dz = pz[k] - ccz;
      f32x2 d = (dx * dx + dy * dy) + dz * dz;
      f32x2 mm = __builtin_elementwise_min(m[k], d);
      m[k] = mm;
      unsigned lo0 = nt - (unsigned)(2 * k) * 512u;       // == ~(p0)
      unsigned lo1 = nt - (unsigned)(2 * k + 1) * 512u;   // == ~(p1)
      double k0 = __longlong_as_double(((unsigned long long)__float_as_uint(mm.x) << 32) | lo0);
      double k1 = __longlong_as_double(((unsigned long long)__float_as_uint(mm.y) << 32) | lo1);
      A = fmax(A, k0);
      B = fmax(B, k1);
    }
    double best = fmax(A, B);
#pragma unroll
    for (int off = 1; off < 64; off <<= 1)
      best = fmax(best, __shfl_xor(best, off));
    if ((t & 63) == 0) kb[par][t >> 6] = best;
    __syncthreads();
    double v0 = fmax(kb[par][0], kb[par][1]);
    double v1 = fmax(kb[par][2], kb[par][3]);
    double v2 = fmax(kb[par][4], kb[par][5]);
    double v3 = fmax(kb[par][6], kb[par][7]);
    const double g = fmax(fmax(v0, v1), fmax(v2, v3));
    const int gidx = (int)(~(unsigned)__double_as_longlong(g));
    const float* q = P + (size_t)gidx * 3;
    cx = q[0]; cy = q[1]; cz = q[2];
    if (t == 0) {
      cidx[b * NG + i] = gidx;
      size_t o = ((size_t)b * NG + i) * 3;
      centers[o] = cx; centers[o + 1] = cy; centers[o + 2] = cz;
      outc[o] = cx; outc[o + 1] = cy; outc[o + 2] = cz;
    }
  }
  if (PHASE < 3) {
#pragma unroll
    for (int k = 0; k < 16; k++) {
      mstate[(size_t)(b * 32 + 2 * k) * 512 + t] = m[k].x;
      mstate[(size_t)(b * 32 + 2 * k + 1) * 512 + t] = m[k].y;
    }
  }
}

// ---------------- KNN + group + x-stat partials (low-LDS, parallel scans) ----------------
// Distances live in registers (dl[32]); no sd[16K] -> ~10.7KB LDS -> 4 blk/CU.
// Bin search: 4-wave __shfl_up inclusive scan + cross-wave offsets; the target
// bin is the unique one with excl < NS <= incl (same bin/cum as the serial
// scan by construction). Selection: single-pass rank-select over boundary-bin
// (value,index) pairs -> exact same selected SET as iterative lex-min
// extraction (row order may differ; all consumers row-permutation-invariant).
__device__ __forceinline__ unsigned wave_iscan(unsigned v, int lane) {
#pragma unroll
  for (int s = 1; s < 64; s <<= 1) {
    unsigned o = (unsigned)__shfl_up((int)v, s);
    if (lane >= s) v += o;
  }
  return v;
}

__global__ __launch_bounds__(512) void k_knn(const float* __restrict__ pts,
                                             const float* __restrict__ centers,
                                             float* __restrict__ group,
                                             float* __restrict__ xpart) {
  __shared__ uint32_t h1[256];
  __shared__ uint32_t h2[256];
  __shared__ int cand_i[1024];
  __shared__ float cand_v[1024];
  __shared__ int sel[32];
  __shared__ float selc[96];
  __shared__ unsigned wsum[4];
  __shared__ int cnts[8];
  __shared__ float redv[8];
  __shared__ int redi[8];
  const int t = threadIdx.x;
  const int lane = t & 63;
  const int bg = blockIdx.x;
  const int b = bg >> 9;
  const float* P = pts + (size_t)b * NP * 3;
  const float cx = centers[bg * 3], cy = centers[bg * 3 + 1], cz = centers[bg * 3 + 2];
  float dl[32];
#pragma unroll
  for (int rr = 0; rr < NP / 512; rr++) {
    int p = rr * 512 + t;
    float dx = __fsub_rn(P[p * 3], cx);
    float dy = __fsub_rn(P[p * 3 + 1], cy);
    float dz = __fsub_rn(P[p * 3 + 2], cz);
    dl[rr] = __fadd_rn(__fadd_rn(__fmul_rn(dx, dx), __fmul_rn(dy, dy)), __fmul_rn(dz, dz));
  }
  if (t < 256) { h1[t] = 0; h2[t] = 0; }
  if (t < 8) cnts[t] = 0;
  __syncthreads();
#pragma unroll
  for (int rr = 0; rr < NP / 512; rr++)
    atomicAdd(&h1[__float_as_uint(dl[rr]) >> 23], 1u);
  __syncthreads();
  // parallel bin search on h1
  unsigned v1 = 0, i1 = 0;
  if (t < 256) {
    v1 = h1[t];
    i1 = wave_iscan(v1, lane);
    if (lane == 63) wsum[t >> 6] = i1;
  }
  __syncthreads();
  if (t < 256) {
    unsigned off = 0;
    for (int q = 0; q < (t >> 6); q++) off += wsum[q];
    unsigned incl = i1 + off, excl = incl - v1;
    if (incl >= NS && excl < NS) { cnts[2] = t; cnts[3] = (int)excl; }
  }
  __syncthreads();
  const uint32_t e1 = (uint32_t)cnts[2];
  const int lt0 = cnts[3];
#pragma unroll
  for (int rr = 0; rr < NP / 512; rr++) {
    uint32_t bits = __float_as_uint(dl[rr]);
    if ((bits >> 23) == e1) atomicAdd(&h2[(bits >> 15) & 255u], 1u);
  }
  __syncthreads();
  unsigned v2 = 0, i2 = 0;
  if (t < 256) {
    v2 = h2[t];
    i2 = wave_iscan(v2, lane);
    if (lane == 63) wsum[t >> 6] = i2;
  }
  __syncthreads();
  if (t < 256) {
    unsigned off = 0;
    for (int q = 0; q < (t >> 6); q++) off += wsum[q];
    unsigned incl = (unsigned)lt0 + i2 + off, excl = incl - v2;
    if (incl >= NS && excl < NS) { cnts[4] = t; cnts[5] = (int)excl; }
  }
  __syncthreads();
  const uint32_t keystar = (e1 << 8) | (uint32_t)cnts[4];
  const int lt = cnts[5];            // strictly-below count, < 32
#pragma unroll
  for (int rr = 0; rr < NP / 512; rr++) {
    int p = rr * 512 + t;
    uint32_t key = __float_as_uint(dl[rr]) >> 15;
    if (key < keystar) { int pos = atomicAdd(&cnts[0], 1); sel[pos] = p; }
    else if (key == keystar) {
      int pos = atomicAdd(&cnts[1], 1);
      if (pos < 1024) { cand_i[pos] = p; cand_v[pos] = dl[rr]; }
    }
  }
  __syncthreads();
  const int neq = cnts[1];
  if (neq <= 1024) {
    // rank-select: one pass (typ. neq << 100)
    const int need = NS - lt;
    for (int e = t; e < neq; e += 512) {
      int p = cand_i[e];
      float v = cand_v[e];
      int rank = 0;
      for (int q = 0; q < neq; q++) {
        int pq = cand_i[q];                 // broadcast LDS reads
        float vq = cand_v[q];
        rank += (vq < v || (vq == v && pq < p)) ? 1 : 0;
      }
      if (rank < need) sel[lt + rank] = p;
    }
    __syncthreads();
  } else {
    // overflow fallback (rare): register-based iterative lex-min extraction
    uint32_t taken = 0;
    for (int j = 0; j < NS; j++) {
      float bv = 3.4e38f; int bp = 0x7FFFFFFF;
#pragma unroll
      for (int rr = 0; rr < NP / 512; rr++) {
        if (!((taken >> rr) & 1u)) {
          float v = dl[rr];
          int p = rr * 512 + t;
          if (v < bv || (v == bv && p < bp)) { bv = v; bp = p; }
        }
      }
#pragma unroll
      for (int off = 32; off >= 1; off >>= 1) {
        float ov = __shfl_xor(bv, off);
        int   op = __shfl_xor(bp, off);
        if (ov < bv || (ov == bv && op < bp)) { bv = ov; bp = op; }
      }
      if (lane == 0) { redv[t >> 6] = bv; redi[t >> 6] = bp; }
      __syncthreads();
      float fv = redv[0]; int fp = redi[0];
      for (int q = 1; q < 8; q++)
        if (redv[q] < fv || (redv[q] == fv && redi[q] < fp)) { fv = redv[q]; fp = redi[q]; }
      if (t == (fp & 511)) taken |= 1u << (fp >> 9);
      if (t == 0) sel[j] = fp;
      __syncthreads();
    }
  }
  if (t < NS) {
    int p = sel[t];
    float gx = __fsub_rn(P[p * 3], cx);
    float gy = __fsub_rn(P[p * 3 + 1], cy);
    float gz = __fsub_rn(P[p * 3 + 2], cz);
    size_t row = ((size_t)bg * NS + t) * 3;
    group[row] = gx; group[row + 1] = gy; group[row + 2] = gz;
    selc[t * 3] = gx; selc[t * 3 + 1] = gy; selc[t * 3 + 2] = gz;
  }
  __syncthreads();
  if (t < 32) {   // parallel x-stats: one row each, 5-step xor-reduce (lanes 0..31)
    float x = selc[t * 3], y = selc[t * 3 + 1], z = selc[t * 3 + 2];
    float s0 = x, s1 = y, s2 = z;
    float s3 = x * x, s4 = y * y, s5 = z * z;
    float s6 = x * y, s7 = x * z, s8 = y * z;
#pragma unroll
    for (int off = 16; off >= 1; off >>= 1) {
      s0 += __shfl_xor(s0, off); s1 += __shfl_xor(s1, off); s2 += __shfl_xor(s2, off);
      s3 += __shfl_xor(s3, off); s4 += __shfl_xor(s4, off); s5 += __shfl_xor(s5, off);
      s6 += __shfl_xor(s6, off); s7 += __shfl_xor(s7, off); s8 += __shfl_xor(s8, off);
    }
    if (t == 0) {
      float* xp = xpart + (size_t)bg * 9;
      xp[0]=s0; xp[1]=s1; xp[2]=s2; xp[3]=s3; xp[4]=s4; xp[5]=s5; xp[6]=s6; xp[7]=s7; xp[8]=s8;
    }
  }
}

// ---------------- BN1 from analytic moments ----------------
__global__ __launch_bounds__(256) void k_bn1(const float* __restrict__ xpart,
                                             const float* __restrict__ w1,
                                             const float* __restrict__ g1,
                                             const float* __restrict__ be1,
                                             float* __restrict__ bn1) {
  __shared__ float wsum[4][9];
  __shared__ float S[9];
  const int t = threadIdx.x;
  float s[9];
#pragma unroll
  for (int j = 0; j < 9; j++) s[j] = 0.f;
  for (int i = t; i < BGT; i += 256) {
    const float* xp = xpart + (size_t)i * 9;
#pragma unroll
    for (int j = 0; j < 9; j++) s[j] += xp[j];
  }
#pragma unroll
  for (int off = 32; off >= 1; off >>= 1)
#pragma unroll
    for (int j = 0; j < 9; j++) s[j] += __shfl_xor(s[j], off);
  if ((t & 63) == 0)
#pragma unroll
    for (int j = 0; j < 9; j++) wsum[t >> 6][j] = s[j];
  __syncthreads();
  if (t == 0)
#pragma unroll
    for (int j = 0; j < 9; j++) S[j] = wsum[0][j] + wsum[1][j] + wsum[2][j] + wsum[3][j];
  __syncthreads();
  if (t < C1) {
    const float rn = 1.0f / (float)NR;
    float ex = S[0]*rn, ey = S[1]*rn, ez = S[2]*rn;
    float exx = S[3]*rn, eyy = S[4]*rn, ezz = S[5]*rn;
    float exy = S[6]*rn, exz = S[7]*rn, eyz = S[8]*rn;
    float a = w1[t*3], b = w1[t*3+1], c = w1[t*3+2];
    float mean = a*ex + b*ey + c*ez;
    float e2 = a*a*exx + b*b*eyy + c*c*ezz + 2.f*(a*b*exy + a*c*exz + b*c*eyz);
    float var = e2 - mean*mean;
    float sc = g1[t] / sqrtf(var + 1e-5f);
    bn1[t*2] = sc;
    bn1[t*2+1] = be1[t] - mean*sc;
  }
}

// ---------------- layer1+2 fused GEMM + fg ----------------
// LDS: xr @0 | a1s1 @1536 | f1A @4096 (32KB) | w2B @36864 (64KB) | f2s @4096 (64KB, reuse)
#define L12_LDS 102400
__global__ __launch_bounds__(512) void k_l12(const float* __restrict__ group,
                                             const float* __restrict__ w1,
                                             const float* __restrict__ bn1,
                                             const ushort* __restrict__ w2b,
                                             const float* __restrict__ b2,
                                             ushort* __restrict__ f2,
                                             float* __restrict__ fg) {
  extern __shared__ char sm[];
  float* xr = (float*)sm;
  float* a1s1 = (float*)(sm + 1536);
  char* f1A = sm + 4096;
  char* w2B = sm + 36864;
  char* f2s = sm + 4096;
  const int t = threadIdx.x;
  const int mb = blockIdx.x;
  const size_t R0 = (size_t)mb * 128;
  if (t < 384) xr[t] = group[R0 * 3 + t];
  if (t < 256) a1s1[t] = bn1[t];
  for (int u = t; u < 4096; u += 512) {      // w2 [256][128] bf16: async, linear LDS,
    int row = u >> 4, c = u & 15;            // inverse-swizzled global src
    gld_lds16((const int4*)w2b + (row * 16 + (c ^ (row & 7))), w2B + u * 16);
  }
  __syncthreads();
  {
    const int c = t & 127;
    const int rb = t >> 7;
    const float wa = w1[c*3], wb = w1[c*3+1], wc = w1[c*3+2];
    const float a1 = a1s1[c*2], s1 = a1s1[c*2+1];
#pragma unroll 4
    for (int i = 0; i < 32; i++) {
      int r = rb * 32 + i;
      float f = xr[r*3] * wa + xr[r*3+1] * wb + xr[r*3+2] * wc;
      float h = fmaxf(fmaf(f, a1, s1), 0.0f);
      *(ushort*)(f1A + r * 256 + ((c * 2) ^ ((r & 7) << 4))) = f2bf(h);
    }
  }
  __syncthreads();
  const int l = t & 63, w = t >> 6;
  const int wm = w >> 2, wn = w & 3;   // 2 x 4 waves, wave tile 64x64
  const int lr = l & 15, lh = l >> 4;
  facc acc[4][4];
#pragma unroll
  for (int tm = 0; tm < 4; tm++)
#pragma unroll
    for (int tn = 0; tn < 4; tn++) acc[tm][tn] = (facc)0.0f;
#pragma unroll
  for (int ks = 0; ks < 4; ks++) {
    const int kb = (ks * 32 + lh * 8) * 2;
    bfrag af[4], bf[4];
#pragma unroll
    for (int tm = 0; tm < 4; tm++) {
      int row = wm * 64 + tm * 16 + lr;
      af[tm] = *(const bfrag*)(f1A + row * 256 + (kb ^ ((row & 7) << 4)));
    }
#pragma unroll
    for (int tn = 0; tn < 4; tn++) {
      int rn = wn * 64 + tn * 16 + lr;
      bf[tn] = *(const bfrag*)(w2B + rn * 256 + (kb ^ ((rn & 7) << 4)));
    }
#pragma unroll
    for (int tm = 0; tm < 4; tm++)
#pragma unroll
      for (int tn = 0; tn < 4; tn++)
        acc[tm][tn] = __builtin_amdgcn_mfma_f32_16x16x32_bf16(af[tm], bf[tn], acc[tm][tn], 0, 0, 0);
  }
  __syncthreads();   // before reusing region as f2s
#pragma unroll
  for (int tn = 0; tn < 4; tn++) {
    int col = wn * 64 + tn * 16 + lr;
    float bb = b2[col];
#pragma unroll
    for (int tm = 0; tm < 4; tm++)
#pragma unroll
      for (int r = 0; r < 4; r++) {
        int row = wm * 64 + tm * 16 + lh * 4 + r;
        *(ushort*)(f2s + row * 512 + ((col * 2) ^ ((row & 7) << 4))) = f2bf(acc[tm][tn][r] + bb);
      }
  }
  __syncthreads();
  for (int u = t; u < 4096; u += 512) {      // f2 tile -> global, [128][256] bf16
    int row = u >> 5, cu = u & 31;
    int4 v = *(const int4*)(f2s + row * 512 + ((cu * 16) ^ ((row & 7) << 4)));
    ((int4*)(f2 + R0 * 256))[u] = v;
  }
  for (int task = t; task < 1024; task += 512) {
    int g = task >> 8, c = task & 255;
    float mx = -3.4e38f;
#pragma unroll 8
    for (int r = 0; r < 32; r++) {
      int row = g * 32 + r;
      mx = fmaxf(mx, bf2f(*(const ushort*)(f2s + row * 512 + ((c * 2) ^ ((row & 7) << 4)))));
    }
    fg[(size_t)(mb * 4 + g) * 256 + c] = mx;
  }
}

// ---------------- fgpart = fg @ w3[:, :256]^T (f32) ----------------
__global__ __launch_bounds__(256) void k_fgpart(const float* __restrict__ fg,
                                                const float* __restrict__ w3,
                                                float* __restrict__ fgpart) {
  __shared__ float fgs[16 * 256];
  const int t = threadIdx.x;
  const int g0 = blockIdx.x * 16;
  for (int i = t; i < 4096; i += 256) fgs[i] = fg[(size_t)g0 * 256 + i];
  __syncthreads();
  for (int half = 0; half < 2; half++) {
    int n = half * 256 + t;
    const float* wr = w3 + (size_t)n * 512;
    float acc[16];
#pragma unroll
    for (int r = 0; r < 16; r++) acc[r] = 0.f;
    for (int k = 0; k < 256; k++) {
      float wv = wr[k];
#pragma unroll
      for (int r = 0; r < 16; r++) acc[r] = fmaf(fgs[r * 256 + k], wv, acc[r]);
    }
#pragma unroll
    for (int r = 0; r < 16; r++) fgpart[(size_t)(g0 + r) * 512 + n] = acc[r];
  }
}

// ---------------- layer3 (+stats) / layer3+4+max (OUT=1) ----------------
// LDS: A @0 (64KB) | B @65536 (64KB) | Hl/stats @131072
#define L34S_LDS 133120
#define L34O_LDS 163840
template <int OUT>
__global__ __launch_bounds__(512) void k_l34(const ushort* __restrict__ f2,
                                             const ushort* __restrict__ w3bb,
                                             const ushort* __restrict__ w4b,
                                             const float* __restrict__ fgpart,
                                             const float* __restrict__ bn3,
                                             const float* __restrict__ b4,
                                             float* __restrict__ partials,
                                             float* __restrict__ tokens) {
  extern __shared__ char sm[];
  char* Al = sm;
  char* Bl = sm + 65536;
  char* Hl = sm + 131072;
  float* st = (float*)(sm + 131072);
  const int t = threadIdx.x;
  const int mb = blockIdx.x;
  const size_t R0 = (size_t)mb * 128;
  const int g0 = mb * 4;
  const int l = t & 63, w = t >> 6;
  const int wm = w >> 2, wn = w & 3;   // 2 x 4 waves
  const int lr = l & 15, lh = l >> 4;
  for (int u = t; u < 4096; u += 512) {      // A: f2 tile, async linear-LDS
    int row = u >> 5, c = u & 31;
    gld_lds16((const int4*)(f2 + R0 * 256) + (row * 32 + (c ^ (row & 7))), Al + u * 16);
  }
  facc tacc[4][6];
  if (OUT) {
#pragma unroll
    for (int tm = 0; tm < 4; tm++)
#pragma unroll
      for (int tn = 0; tn < 6; tn++) tacc[tm][tn] = (facc)0.0f;
  }
  for (int kc = 0; kc < 4; kc++) {
    for (int u = t; u < 4096; u += 512) {    // B: w3bb rows [kc*128,+128), async
      int row = u >> 5, c = u & 31;
      gld_lds16((const int4*)(w3bb + (size_t)kc * 128 * 256) + (row * 32 + (c ^ (row & 7))),
                Bl + u * 16);
    }
    __syncthreads();
    facc acc[4][2];
#pragma unroll
    for (int tm = 0; tm < 4; tm++) { acc[tm][0] = (facc)0.0f; acc[tm][1] = (facc)0.0f; }
#pragma unroll
    for (int ks = 0; ks < 8; ks++) {
      const int kb = (ks * 32 + lh * 8) * 2;
      bfrag af[4], bf[2];
#pragma unroll
      for (int tm = 0; tm < 4; tm++) {
        int row = wm * 64 + tm * 16 + lr;
        af[tm] = *(const bfrag*)(Al + row * 512 + (kb ^ ((row & 7) << 4)));
      }
#pragma unroll
      for (int tn = 0; tn < 2; tn++) {
        int rn = wn * 32 + tn * 16 + lr;
        bf[tn] = *(const bfrag*)(Bl + rn * 512 + (kb ^ ((rn & 7) << 4)));
      }
#pragma unroll
      for (int tm = 0; tm < 4; tm++)
#pragma unroll
        for (int tn = 0; tn < 2; tn++)
          acc[tm][tn] = __builtin_amdgcn_mfma_f32_16x16x32_bf16(af[tm], bf[tn], acc[tm][tn], 0, 0, 0);
    }
    float fgp0[2], fgp1[2], a3c[2], s3c[2];
#pragma unroll
    for (int tn = 0; tn < 2; tn++) {
      int col = kc * 128 + wn * 32 + tn * 16 + lr;
      fgp0[tn] = fgpart[(size_t)(g0 + wm * 2) * 512 + col];
      fgp1[tn] = fgpart[(size_t)(g0 + wm * 2 + 1) * 512 + col];
      if (OUT) { a3c[tn] = bn3[col * 2]; s3c[tn] = bn3[col * 2 + 1]; }
    }
    if (OUT == 0) {
      float s1v[2] = {0.f, 0.f}, s2v[2] = {0.f, 0.f};
#pragma unroll
      for (int tm = 0; tm < 4; tm++)
#pragma unroll
        for (int tn = 0; tn < 2; tn++)
#pragma unroll
          for (int r = 0; r < 4; r++) {
            float f3 = acc[tm][tn][r] + (tm < 2 ? fgp0[tn] : fgp1[tn]);
            s1v[tn] += f3; s2v[tn] += f3 * f3;
          }
#pragma unroll
      for (int tn = 0; tn < 2; tn++) {
        s1v[tn] += __shfl_xor(s1v[tn], 16); s1v[tn] += __shfl_xor(s1v[tn], 32);
        s2v[tn] += __shfl_xor(s2v[tn], 16); s2v[tn] += __shfl_xor(s2v[tn], 32);
      }
      if (l < 16) {
#pragma unroll
        for (int tn = 0; tn < 2; tn++) {
          int cl = wn * 32 + tn * 16 + lr;
          st[(wm * 128 + cl) * 2 + 0] = s1v[tn];
          st[(wm * 128 + cl) * 2 + 1] = s2v[tn];
        }
      }
      __syncthreads();
      if (t < 256) {
        int cl = t & 127, s = t >> 7;
        float tot = st[(0 * 128 + cl) * 2 + s] + st[(1 * 128 + cl) * 2 + s];
        partials[(size_t)mb * 1024 + (size_t)(kc * 128 + cl) * 2 + s] = tot;
      }
      __syncthreads();
    } else {
#pragma unroll
      for (int tm = 0; tm < 4; tm++)
#pragma unroll
        for (int tn = 0; tn < 2; tn++)
#pragma unroll
          for (int r = 0; r < 4; r++) {
            int row = wm * 64 + tm * 16 + lh * 4 + r;
            int cl = wn * 32 + tn * 16 + lr;
            float f3 = acc[tm][tn][r] + (tm < 2 ? fgp0[tn] : fgp1[tn]);
            float hv = fmaxf(fmaf(f3, a3c[tn], s3c[tn]), 0.0f);
            *(ushort*)(Hl + row * 256 + ((cl * 2) ^ ((row & 7) << 4))) = f2bf(hv);
          }
      __syncthreads();  // h ready; B free
#pragma unroll
      for (int p = 0; p < 2; p++) {
        for (int u = t; u < 3072; u += 512) {   // w4 piece [384][64] bf16, async
          int row = u >> 3, c = u & 7;
          gld_lds16((const int4*)(w4b + (size_t)row * 512 + kc * 128 + p * 64) + (c ^ (row & 7)),
                    Bl + u * 16);
        }
        __syncthreads();
#pragma unroll
        for (int ks = 0; ks < 2; ks++) {
          const int kbh = (p * 64 + ks * 32 + lh * 8) * 2;
          const int kbb = (ks * 32 + lh * 8) * 2;
          bfrag af[4], bf[6];
#pragma unroll
          for (int tm = 0; tm < 4; tm++) {
            int row = wm * 64 + tm * 16 + lr;
            af[tm] = *(const bfrag*)(Hl + row * 256 + (kbh ^ ((row & 7) << 4)));
          }
#pragma unroll
          for (int tn = 0; tn < 6; tn++) {
            int rn = wn * 96 + tn * 16 + lr;
            bf[tn] = *(const bfrag*)(Bl + rn * 128 + (kbb ^ ((rn & 7) << 4)));
          }
#pragma unroll
          for (int tm = 0; tm < 4; tm++)
#pragma unroll
            for (int tn = 0; tn < 6; tn++)
              tacc[tm][tn] = __builtin_amdgcn_mfma_f32_16x16x32_bf16(af[tm], bf[tn], tacc[tm][tn], 0, 0, 0);
        }
        __syncthreads();
      }
    }
  }
  if (OUT) {
#pragma unroll
    for (int tn = 0; tn < 6; tn++) {
      int col = wn * 96 + tn * 16 + lr;
      float bb = b4[col];
#pragma unroll
      for (int half = 0; half < 2; half++) {
        float mx = -3.4e38f;
#pragma unroll
        for (int tm = half * 2; tm < half * 2 + 2; tm++)
#pragma unroll
          for (int r = 0; r < 4; r++) mx = fmaxf(mx, tacc[tm][tn][r]);
        mx = fmaxf(mx, __shfl_xor(mx, 16));
        mx = fmaxf(mx, __shfl_xor(mx, 32));
        if (l < 16) tokens[(size_t)(g0 + wm * 2 + half) * TDM + col] = mx + bb;
      }
    }
  }
}

// ---------------- BN3 finalize (1024 thr: 8-way chunked sum + LDS reduce) ----------------
__global__ __launch_bounds__(1024) void k_bn3(const float* __restrict__ partials,
                                              const float* __restrict__ g3,
                                              const float* __restrict__ be3,
                                              float* __restrict__ bn3) {
  __shared__ float ls[128][8];
  const int t = threadIdx.x;
  const int slot_l = t & 127;          // slot within this block's 128
  const int chunk = t >> 7;            // 0..7
  const int slot = blockIdx.x * 128 + slot_l;
  float s = 0.f;
  for (int m = chunk * 128; m < chunk * 128 + 128; m++)
    s += partials[(size_t)m * 1024 + slot];
  ls[slot_l][chunk] = s;
  __syncthreads();
  if (t < 64) {
    int col = blockIdx.x * 64 + t;
    float s1 = 0.f, s2 = 0.f;
#pragma unroll
    for (int c = 0; c < 8; c++) { s1 += ls[2 * t][c]; s2 += ls[2 * t + 1][c]; }
    const float rn = 1.0f / (float)NR;
    float mean = s1 * rn;
    float var = s2 * rn - mean * mean;
    float a = g3[col] / sqrtf(var + 1e-5f);
    bn3[col * 2] = a;
    bn3[col * 2 + 1] = be3[col] - mean * a;
  }
}

extern "C" void kernel_launch(void* const* d_in, const int* in_sizes, int n_in,
                              void* d_out, int out_size, void* d_ws, size_t ws_size,
                              hipStream_t stream) {
  const float* points = (const float*)d_in[0];
  const float* w1 = (const float*)d_in[2];
  const float* g1 = (const float*)d_in[3];
  const float* be1 = (const float*)d_in[4];
  const float* w2 = (const float*)d_in[5];
  const float* b2 = (const float*)d_in[6];
  const float* w3 = (const float*)d_in[7];
  const float* g3 = (const float*)d_in[8];
  const float* be3 = (const float*)d_in[9];
  const float* w4 = (const float*)d_in[10];
  const float* b4 = (const float*)d_in[11];
  char* ws = (char*)d_ws;
  int* cidx = (int*)(ws + OFF_CIDX);
  float* centers = (float*)(ws + OFF_CENT);
  float* group = (float*)(ws + OFF_GROUP);
  float* xpart = (float*)(ws + OFF_XPART);
  float* bn1 = (float*)(ws + OFF_BN1);
  float* bn3 = (float*)(ws + OFF_BN3);
  ushort* w2b = (ushort*)(ws + OFF_W2B);
  ushort* w3bb = (ushort*)(ws + OFF_W3BB);
  ushort* w4b = (ushort*)(ws + OFF_W4B);
  float* fg = (float*)(ws + OFF_FG);
  float* fgpart = (float*)(ws + OFF_FGP);
  float* partials = (float*)(ws + OFF_PART);
  ushort* f2 = (ushort*)(ws + OFF_F2);
  float* out = (float*)d_out;
  float* out_centers = out + (size_t)BGT * TDM;
  float* out_mask = out_centers + (size_t)BGT * 3;

  hipFuncSetAttribute((const void*)k_l12, hipFuncAttributeMaxDynamicSharedMemorySize, L12_LDS);
  {
    auto p0 = k_l34<0>; auto p1 = k_l34<1>;
    hipFuncSetAttribute((const void*)p0, hipFuncAttributeMaxDynamicSharedMemorySize, L34S_LDS);
    hipFuncSetAttribute((const void*)p1, hipFuncAttributeMaxDynamicSharedMemorySize, L34O_LDS);
  }

  float* mstate = (float*)(ws + OFF_PART);   // dead until l34<0> writes partials

  // phase 0 carries 712 prep blocks (weight convert + mask) on idle CUs
  k_fps<0><<<NB + 712, 512, 0, stream>>>(points, cidx, centers, out_centers, mstate,
                                         w2, w3, w4, w2b, w3bb, w4b, out_mask);
  k_fps<1><<<NB, 512, 0, stream>>>(points, cidx, centers, out_centers, mstate,
                                   w2, w3, w4, w2b, w3bb, w4b, out_mask);
  k_fps<2><<<NB, 512, 0, stream>>>(points, cidx, centers, out_centers, mstate,
                                   w2, w3, w4, w2b, w3bb, w4b, out_mask);
  k_fps<3><<<NB, 512, 0, stream>>>(points, cidx, centers, out_centers, mstate,
                                   w2, w3, w4, w2b, w3bb, w4b, out_mask);
  k_knn<<<BGT, 512, 0, stream>>>(points, centers, group, xpart);
  k_bn1<<<1, 256, 0, stream>>>(xpart, w1, g1, be1, bn1);
  k_l12<<<NR / 128, 512, L12_LDS, stream>>>(group, w1, bn1, w2b, b2, f2, fg);
  k_fgpart<<<BGT / 16, 256, 0, stream>>>(fg, w3, fgpart);
  k_l34<0><<<NR / 128, 512, L34S_LDS, stream>>>(f2, w3bb, nullptr, fgpart, nullptr, nullptr, partials, nullptr);
  k_bn3<<<8, 1024, 0, stream>>>(partials, g3, be3, bn3);
  k_l34<1><<<NR / 128, 512, L34O_LDS, stream>>>(f2, w3bb, w4b, fgpart, bn3, b4, nullptr, out);
}

// Round 14
// 1215.406 us; speedup vs baseline: 1.1291x; 1.0378x over previous
//
#include <hip/hip_runtime.h>
#include <hip/hip_bf16.h>
#include <cstdint>

#define NB 8
#define NP 16384
#define NG 512
#define NS 32
#define TDM 384
#define BGT (NB*NG)        // 4096 groups total
#define NR (BGT*NS)        // 131072 rows
#define C1 128
#define C2 256
#define C3 512

typedef __attribute__((ext_vector_type(8))) short bfrag;   // 8 bf16
typedef __attribute__((ext_vector_type(4))) float facc;    // 4 f32
typedef __attribute__((ext_vector_type(2))) float f32x2;

__device__ __forceinline__ ushort f2bf(float f) {
  uint32_t u = __float_as_uint(f);
  uint32_t r = (u + 0x7FFFu + ((u >> 16) & 1u)) >> 16;  // RNE
  return (ushort)r;
}
__device__ __forceinline__ float bf2f(ushort h) {
  return __uint_as_float(((uint32_t)h) << 16);
}

// async global->LDS, 16B per lane. LDS dst must be linear in lane order
// (wave-uniform base + lane*16); swizzled layouts are achieved by
// inverse-swizzling the per-lane GLOBAL source (m104/m173 pattern).
__device__ __forceinline__ void gld_lds16(const void* g, void* l) {
  __builtin_amdgcn_global_load_lds(
      (const __attribute__((address_space(1))) void*)g,
      (__attribute__((address_space(3))) void*)l, 16, 0, 0);
}

// ---------------- ws layout (bytes) ----------------
#define OFF_CIDX   0u
#define OFF_CENT   16384u
#define OFF_GROUP  65536u      // 131072*3*4 = 1572864
#define OFF_XPART  1638400u    // 4096*9*4   = 147456
#define OFF_BN1    1785856u    // 128*2*4
#define OFF_BN3    1786880u    // 512*2*4
#define OFF_W2B    1790976u    // 32768*2
#define OFF_W3BB   1856512u    // 131072*2
#define OFF_W4B    2118656u    // 196608*2
#define OFF_FG     2511872u    // 4096*256*4 = 4194304
#define OFF_FGP    6706176u    // 4096*512*4 = 8388608
#define OFF_PART   15094784u   // 1024*1024*4 = 4194304 (also fps m-state: 512KB, dead until l34<0>)
#define OFF_F2     19289088u   // 131072*256*2 = 67108864  -> end 86397952

// ---------------- FPS (4 phases of 128 iters) + prep folded into phase 0 ----------------
template <int PHASE>
__global__ __launch_bounds__(512, 2) void k_fps(const float* __restrict__ pts,
                                                int* __restrict__ cidx,
                                                float* __restrict__ centers,
                                                float* __restrict__ outc,
                                                float* __restrict__ mstate,
                                                const float* __restrict__ w2,
                                                const float* __restrict__ w3,
                                                const float* __restrict__ w4,
                                                ushort* __restrict__ w2b,
                                                ushort* __restrict__ w3bb,
                                                ushort* __restrict__ w4b,
                                                float* __restrict__ mask) {
#pragma clang fp contract(off)
  const int t = threadIdx.x;
  if (PHASE == 0 && blockIdx.x >= NB) {      // prep blocks (idle CUs)
    int i = (blockIdx.x - NB) * 512 + t;
    if (i < 32768) {
      int r = i >> 7, c = i & 127;
      w2b[i] = f2bf(w2[r * 128 + c]);
    } else if (i < 163840) {
      int j = i - 32768; int r = j >> 8, c = j & 255;
      w3bb[j] = f2bf(w3[(size_t)r * 512 + 256 + c]);
    } else if (i < 360448) {
      int j = i - 163840; int r = j >> 9, c = j & 511;
      w4b[j] = f2bf(w4[(size_t)r * 512 + c]);
    } else if (i < 364544) {
      mask[i - 360448] = 1.0f;
    }
    return;
  }
  const int b = blockIdx.x;
  const float* P = pts + (size_t)b * NP * 3;
  f32x2 px[16], py[16], pz[16], m[16];
#pragma unroll
  for (int k = 0; k < 16; k++) {
    int p0 = (2 * k) * 512 + t;
    int p1 = p0 + 512;
    px[k] = (f32x2){P[p0 * 3 + 0], P[p1 * 3 + 0]};
    py[k] = (f32x2){P[p0 * 3 + 1], P[p1 * 3 + 1]};
    pz[k] = (f32x2){P[p0 * 3 + 2], P[p1 * 3 + 2]};
    if (PHASE == 0) {
      m[k] = (f32x2){1e10f, 1e10f};
    } else {
      m[k].x = mstate[(size_t)(b * 32 + 2 * k) * 512 + t];
      m[k].y = mstate[(size_t)(b * 32 + 2 * k + 1) * 512 + t];
    }
  }
  __shared__ double kb[2][8];
  float cx, cy, cz;
  if (PHASE == 0) {
    cx = P[0]; cy = P[1]; cz = P[2];
    if (t == 0) {
      cidx[b * NG] = 0;
      size_t o = (size_t)b * NG * 3;
      centers[o] = cx; centers[o + 1] = cy; centers[o + 2] = cz;
      outc[o] = cx; outc[o + 1] = cy; outc[o + 2] = cz;
    }
  } else {
    size_t o = ((size_t)b * NG + (PHASE * 128 - 1)) * 3;
    cx = centers[o]; cy = centers[o + 1]; cz = centers[o + 2];
  }
  const unsigned nt = ~(unsigned)t;
  const int i_beg = (PHASE == 0) ? 1 : PHASE * 128;
  const int i_end = (PHASE + 1) * 128;
  for (int i = i_beg; i < i_end; i++) {
    const int par = i & 1;
    const f32x2 ccx = (f32x2){cx, cx};
    const f32x2 ccy = (f32x2){cy, cy};
    const f32x2 ccz = (f32x2){cz, cz};
    double A = 0.0, B = 0.0;   // 2 independent 8-deep max chains
#pragma unroll
    for (int k = 0; k < 16; k++) {
      // exact reference arithmetic: sub, mul, (x2+y2)+z2, no fma (contract off)
      f32x2 dx = px[k] - ccx;
      f32x2 dy = py[k] - ccy;
      f32x2 dz = pz[k] - ccz;
      f32x2 d = (dx * dx + dy * dy) + dz * dz;
      f32x2 mm = __builtin_elementwise_min(m[k], d);
      m[k] = mm;
      unsigned lo0 = nt - (unsigned)(2 * k) * 512u;       // == ~(p0)
      unsigned lo1 = nt - (unsigned)(2 * k + 1) * 512u;   // == ~(p1)
      double k0 = __longlong_as_double(((unsigned long long)__float_as_uint(mm.x) << 32) | lo0);
      double k1 = __longlong_as_double(((unsigned long long)__float_as_uint(mm.y) << 32) | lo1);
      A = fmax(A, k0);
      B = fmax(B, k1);
    }
    double best = fmax(A, B);
#pragma unroll
    for (int off = 1; off < 64; off <<= 1)
      best = fmax(best, __shfl_xor(best, off));
    if ((t & 63) == 0) kb[par][t >> 6] = best;
    __syncthreads();
    double v0 = fmax(kb[par][0], kb[par][1]);
    double v1 = fmax(kb[par][2], kb[par][3]);
    double v2 = fmax(kb[par][4], kb[par][5]);
    double v3 = fmax(kb[par][6], kb[par][7]);
    const double g = fmax(fmax(v0, v1), fmax(v2, v3));
    const int gidx = (int)(~(unsigned)__double_as_longlong(g));
    const float* q = P + (size_t)gidx * 3;
    cx = q[0]; cy = q[1]; cz = q[2];
    if (t == 0) {
      cidx[b * NG + i] = gidx;
      size_t o = ((size_t)b * NG + i) * 3;
      centers[o] = cx; centers[o + 1] = cy; centers[o + 2] = cz;
      outc[o] = cx; outc[o + 1] = cy; outc[o + 2] = cz;
    }
  }
  if (PHASE < 3) {
#pragma unroll
    for (int k = 0; k < 16; k++) {
      mstate[(size_t)(b * 32 + 2 * k) * 512 + t] = m[k].x;
      mstate[(size_t)(b * 32 + 2 * k + 1) * 512 + t] = m[k].y;
    }
  }
}

// ---------------- KNN + group + x-stat partials (low-LDS, parallel scans) ----------------
// Distances in registers (dl[32]). Histograms are 4-way sub-banked:
// lane l atomics into copy l&3 of h[4][257] -> within-wave same-bin
// serialization drops from <=64-way to <=16-way; pad 257 de-banks the
// copies. Scan sums the 4 copies per bin (integer counts, order-free ->
// bin/cum bit-identical to single-copy). Selection: rank-select (exact
// same selected SET as iterative lex-min; row order irrelevant).
__device__ __forceinline__ unsigned wave_iscan(unsigned v, int lane) {
#pragma unroll
  for (int s = 1; s < 64; s <<= 1) {
    unsigned o = (unsigned)__shfl_up((int)v, s);
    if (lane >= s) v += o;
  }
  return v;
}

__global__ __launch_bounds__(512) void k_knn(const float* __restrict__ pts,
                                             const float* __restrict__ centers,
                                             float* __restrict__ group,
                                             float* __restrict__ xpart) {
  __shared__ uint32_t h1[4][257];
  __shared__ uint32_t h2[4][257];
  __shared__ int cand_i[1024];
  __shared__ float cand_v[1024];
  __shared__ int sel[32];
  __shared__ float selc[96];
  __shared__ unsigned wsum[4];
  __shared__ int cnts[8];
  __shared__ float redv[8];
  __shared__ int redi[8];
  const int t = threadIdx.x;
  const int lane = t & 63;
  const int cp = lane & 3;
  const int bg = blockIdx.x;
  const int b = bg >> 9;
  const float* P = pts + (size_t)b * NP * 3;
  const float cx = centers[bg * 3], cy = centers[bg * 3 + 1], cz = centers[bg * 3 + 2];
  float dl[32];
#pragma unroll
  for (int rr = 0; rr < NP / 512; rr++) {
    int p = rr * 512 + t;
    float dx = __fsub_rn(P[p * 3], cx);
    float dy = __fsub_rn(P[p * 3 + 1], cy);
    float dz = __fsub_rn(P[p * 3 + 2], cz);
    dl[rr] = __fadd_rn(__fadd_rn(__fmul_rn(dx, dx), __fmul_rn(dy, dy)), __fmul_rn(dz, dz));
  }
  for (int u = t; u < 4 * 257; u += 512) { h1[0][u] = 0; h2[0][u] = 0; }  // flat zero both
  if (t < 8) cnts[t] = 0;
  __syncthreads();
#pragma unroll
  for (int rr = 0; rr < NP / 512; rr++)
    atomicAdd(&h1[cp][__float_as_uint(dl[rr]) >> 23], 1u);
  __syncthreads();
  // parallel bin search on h1 (sum of 4 copies per bin)
  unsigned v1 = 0, i1 = 0;
  if (t < 256) {
    v1 = h1[0][t] + h1[1][t] + h1[2][t] + h1[3][t];
    i1 = wave_iscan(v1, lane);
    if (lane == 63) wsum[t >> 6] = i1;
  }
  __syncthreads();
  if (t < 256) {
    unsigned off = 0;
    for (int q = 0; q < (t >> 6); q++) off += wsum[q];
    unsigned incl = i1 + off, excl = incl - v1;
    if (incl >= NS && excl < NS) { cnts[2] = t; cnts[3] = (int)excl; }
  }
  __syncthreads();
  const uint32_t e1 = (uint32_t)cnts[2];
  const int lt0 = cnts[3];
#pragma unroll
  for (int rr = 0; rr < NP / 512; rr++) {
    uint32_t bits = __float_as_uint(dl[rr]);
    if ((bits >> 23) == e1) atomicAdd(&h2[cp][(bits >> 15) & 255u], 1u);
  }
  __syncthreads();
  unsigned v2 = 0, i2 = 0;
  if (t < 256) {
    v2 = h2[0][t] + h2[1][t] + h2[2][t] + h2[3][t];
    i2 = wave_iscan(v2, lane);
    if (lane == 63) wsum[t >> 6] = i2;
  }
  __syncthreads();
  if (t < 256) {
    unsigned off = 0;
    for (int q = 0; q < (t >> 6); q++) off += wsum[q];
    unsigned incl = (unsigned)lt0 + i2 + off, excl = incl - v2;
    if (incl >= NS && excl < NS) { cnts[4] = t; cnts[5] = (int)excl; }
  }
  __syncthreads();
  const uint32_t keystar = (e1 << 8) | (uint32_t)cnts[4];
  const int lt = cnts[5];            // strictly-below count, < 32
#pragma unroll
  for (int rr = 0; rr < NP / 512; rr++) {
    int p = rr * 512 + t;
    uint32_t key = __float_as_uint(dl[rr]) >> 15;
    if (key < keystar) { int pos = atomicAdd(&cnts[0], 1); sel[pos] = p; }
    else if (key == keystar) {
      int pos = atomicAdd(&cnts[1], 1);
      if (pos < 1024) { cand_i[pos] = p; cand_v[pos] = dl[rr]; }
    }
  }
  __syncthreads();
  const int neq = cnts[1];
  if (neq <= 1024) {
    // rank-select: one pass (typ. neq << 100)
    const int need = NS - lt;
    for (int e = t; e < neq; e += 512) {
      int p = cand_i[e];
      float v = cand_v[e];
      int rank = 0;
      for (int q = 0; q < neq; q++) {
        int pq = cand_i[q];                 // broadcast LDS reads
        float vq = cand_v[q];
        rank += (vq < v || (vq == v && pq < p)) ? 1 : 0;
      }
      if (rank < need) sel[lt + rank] = p;
    }
    __syncthreads();
  } else {
    // overflow fallback (rare): register-based iterative lex-min extraction
    uint32_t taken = 0;
    for (int j = 0; j < NS; j++) {
      float bv = 3.4e38f; int bp = 0x7FFFFFFF;
#pragma unroll
      for (int rr = 0; rr < NP / 512; rr++) {
        if (!((taken >> rr) & 1u)) {
          float v = dl[rr];
          int p = rr * 512 + t;
          if (v < bv || (v == bv && p < bp)) { bv = v; bp = p; }
        }
      }
#pragma unroll
      for (int off = 32; off >= 1; off >>= 1) {
        float ov = __shfl_xor(bv, off);
        int   op = __shfl_xor(bp, off);
        if (ov < bv || (ov == bv && op < bp)) { bv = ov; bp = op; }
      }
      if (lane == 0) { redv[t >> 6] = bv; redi[t >> 6] = bp; }
      __syncthreads();
      float fv = redv[0]; int fp = redi[0];
      for (int q = 1; q < 8; q++)
        if (redv[q] < fv || (redv[q] == fv && redi[q] < fp)) { fv = redv[q]; fp = redi[q]; }
      if (t == (fp & 511)) taken |= 1u << (fp >> 9);
      if (t == 0) sel[j] = fp;
      __syncthreads();
    }
  }
  if (t < NS) {
    int p = sel[t];
    float gx = __fsub_rn(P[p * 3], cx);
    float gy = __fsub_rn(P[p * 3 + 1], cy);
    float gz = __fsub_rn(P[p * 3 + 2], cz);
    size_t row = ((size_t)bg * NS + t) * 3;
    group[row] = gx; group[row + 1] = gy; group[row + 2] = gz;
    selc[t * 3] = gx; selc[t * 3 + 1] = gy; selc[t * 3 + 2] = gz;
  }
  __syncthreads();
  if (t < 32) {   // parallel x-stats: one row each, 5-step xor-reduce (lanes 0..31)
    float x = selc[t * 3], y = selc[t * 3 + 1], z = selc[t * 3 + 2];
    float s0 = x, s1 = y, s2 = z;
    float s3 = x * x, s4 = y * y, s5 = z * z;
    float s6 = x * y, s7 = x * z, s8 = y * z;
#pragma unroll
    for (int off = 16; off >= 1; off >>= 1) {
      s0 += __shfl_xor(s0, off); s1 += __shfl_xor(s1, off); s2 += __shfl_xor(s2, off);
      s3 += __shfl_xor(s3, off); s4 += __shfl_xor(s4, off); s5 += __shfl_xor(s5, off);
      s6 += __shfl_xor(s6, off); s7 += __shfl_xor(s7, off); s8 += __shfl_xor(s8, off);
    }
    if (t == 0) {
      float* xp = xpart + (size_t)bg * 9;
      xp[0]=s0; xp[1]=s1; xp[2]=s2; xp[3]=s3; xp[4]=s4; xp[5]=s5; xp[6]=s6; xp[7]=s7; xp[8]=s8;
    }
  }
}

// ---------------- BN1 from analytic moments ----------------
__global__ __launch_bounds__(256) void k_bn1(const float* __restrict__ xpart,
                                             const float* __restrict__ w1,
                                             const float* __restrict__ g1,
                                             const float* __restrict__ be1,
                                             float* __restrict__ bn1) {
  __shared__ float wsum[4][9];
  __shared__ float S[9];
  const int t = threadIdx.x;
  float s[9];
#pragma unroll
  for (int j = 0; j < 9; j++) s[j] = 0.f;
  for (int i = t; i < BGT; i += 256) {
    const float* xp = xpart + (size_t)i * 9;
#pragma unroll
    for (int j = 0; j < 9; j++) s[j] += xp[j];
  }
#pragma unroll
  for (int off = 32; off >= 1; off >>= 1)
#pragma unroll
    for (int j = 0; j < 9; j++) s[j] += __shfl_xor(s[j], off);
  if ((t & 63) == 0)
#pragma unroll
    for (int j = 0; j < 9; j++) wsum[t >> 6][j] = s[j];
  __syncthreads();
  if (t == 0)
#pragma unroll
    for (int j = 0; j < 9; j++) S[j] = wsum[0][j] + wsum[1][j] + wsum[2][j] + wsum[3][j];
  __syncthreads();
  if (t < C1) {
    const float rn = 1.0f / (float)NR;
    float ex = S[0]*rn, ey = S[1]*rn, ez = S[2]*rn;
    float exx = S[3]*rn, eyy = S[4]*rn, ezz = S[5]*rn;
    float exy = S[6]*rn, exz = S[7]*rn, eyz = S[8]*rn;
    float a = w1[t*3], b = w1[t*3+1], c = w1[t*3+2];
    float mean = a*ex + b*ey + c*ez;
    float e2 = a*a*exx + b*b*eyy + c*c*ezz + 2.f*(a*b*exy + a*c*exz + b*c*eyz);
    float var = e2 - mean*mean;
    float sc = g1[t] / sqrtf(var + 1e-5f);
    bn1[t*2] = sc;
    bn1[t*2+1] = be1[t] - mean*sc;
  }
}

// ---------------- layer1+2 fused GEMM + fg ----------------
// LDS: xr @0 | a1s1 @1536 | f1A @4096 (32KB) | w2B @36864 (64KB) | f2s @4096 (64KB, reuse)
#define L12_LDS 102400
__global__ __launch_bounds__(512) void k_l12(const float* __restrict__ group,
                                             const float* __restrict__ w1,
                                             const float* __restrict__ bn1,
                                             const ushort* __restrict__ w2b,
                                             const float* __restrict__ b2,
                                             ushort* __restrict__ f2,
                                             float* __restrict__ fg) {
  extern __shared__ char sm[];
  float* xr = (float*)sm;
  float* a1s1 = (float*)(sm + 1536);
  char* f1A = sm + 4096;
  char* w2B = sm + 36864;
  char* f2s = sm + 4096;
  const int t = threadIdx.x;
  const int mb = blockIdx.x;
  const size_t R0 = (size_t)mb * 128;
  if (t < 384) xr[t] = group[R0 * 3 + t];
  if (t < 256) a1s1[t] = bn1[t];
  for (int u = t; u < 4096; u += 512) {      // w2 [256][128] bf16: async, linear LDS,
    int row = u >> 4, c = u & 15;            // inverse-swizzled global src
    gld_lds16((const int4*)w2b + (row * 16 + (c ^ (row & 7))), w2B + u * 16);
  }
  __syncthreads();
  {
    const int c = t & 127;
    const int rb = t >> 7;
    const float wa = w1[c*3], wb = w1[c*3+1], wc = w1[c*3+2];
    const float a1 = a1s1[c*2], s1 = a1s1[c*2+1];
#pragma unroll 4
    for (int i = 0; i < 32; i++) {
      int r = rb * 32 + i;
      float f = xr[r*3] * wa + xr[r*3+1] * wb + xr[r*3+2] * wc;
      float h = fmaxf(fmaf(f, a1, s1), 0.0f);
      *(ushort*)(f1A + r * 256 + ((c * 2) ^ ((r & 7) << 4))) = f2bf(h);
    }
  }
  __syncthreads();
  const int l = t & 63, w = t >> 6;
  const int wm = w >> 2, wn = w & 3;   // 2 x 4 waves, wave tile 64x64
  const int lr = l & 15, lh = l >> 4;
  facc acc[4][4];
#pragma unroll
  for (int tm = 0; tm < 4; tm++)
#pragma unroll
    for (int tn = 0; tn < 4; tn++) acc[tm][tn] = (facc)0.0f;
#pragma unroll
  for (int ks = 0; ks < 4; ks++) {
    const int kb = (ks * 32 + lh * 8) * 2;
    bfrag af[4], bf[4];
#pragma unroll
    for (int tm = 0; tm < 4; tm++) {
      int row = wm * 64 + tm * 16 + lr;
      af[tm] = *(const bfrag*)(f1A + row * 256 + (kb ^ ((row & 7) << 4)));
    }
#pragma unroll
    for (int tn = 0; tn < 4; tn++) {
      int rn = wn * 64 + tn * 16 + lr;
      bf[tn] = *(const bfrag*)(w2B + rn * 256 + (kb ^ ((rn & 7) << 4)));
    }
#pragma unroll
    for (int tm = 0; tm < 4; tm++)
#pragma unroll
      for (int tn = 0; tn < 4; tn++)
        acc[tm][tn] = __builtin_amdgcn_mfma_f32_16x16x32_bf16(af[tm], bf[tn], acc[tm][tn], 0, 0, 0);
  }
  __syncthreads();   // before reusing region as f2s
#pragma unroll
  for (int tn = 0; tn < 4; tn++) {
    int col = wn * 64 + tn * 16 + lr;
    float bb = b2[col];
#pragma unroll
    for (int tm = 0; tm < 4; tm++)
#pragma unroll
      for (int r = 0; r < 4; r++) {
        int row = wm * 64 + tm * 16 + lh * 4 + r;
        *(ushort*)(f2s + row * 512 + ((col * 2) ^ ((row & 7) << 4))) = f2bf(acc[tm][tn][r] + bb);
      }
  }
  __syncthreads();
  for (int u = t; u < 4096; u += 512) {      // f2 tile -> global, [128][256] bf16
    int row = u >> 5, cu = u & 31;
    int4 v = *(const int4*)(f2s + row * 512 + ((cu * 16) ^ ((row & 7) << 4)));
    ((int4*)(f2 + R0 * 256))[u] = v;
  }
  for (int task = t; task < 1024; task += 512) {
    int g = task >> 8, c = task & 255;
    float mx = -3.4e38f;
#pragma unroll 8
    for (int r = 0; r < 32; r++) {
      int row = g * 32 + r;
      mx = fmaxf(mx, bf2f(*(const ushort*)(f2s + row * 512 + ((c * 2) ^ ((row & 7) << 4)))));
    }
    fg[(size_t)(mb * 4 + g) * 256 + c] = mx;
  }
}

// ---------------- fgpart = fg @ w3[:, :256]^T (f32) ----------------
__global__ __launch_bounds__(256) void k_fgpart(const float* __restrict__ fg,
                                                const float* __restrict__ w3,
                                                float* __restrict__ fgpart) {
  __shared__ float fgs[16 * 256];
  const int t = threadIdx.x;
  const int g0 = blockIdx.x * 16;
  for (int i = t; i < 4096; i += 256) fgs[i] = fg[(size_t)g0 * 256 + i];
  __syncthreads();
  for (int half = 0; half < 2; half++) {
    int n = half * 256 + t;
    const float* wr = w3 + (size_t)n * 512;
    float acc[16];
#pragma unroll
    for (int r = 0; r < 16; r++) acc[r] = 0.f;
    for (int k = 0; k < 256; k++) {
      float wv = wr[k];
#pragma unroll
      for (int r = 0; r < 16; r++) acc[r] = fmaf(fgs[r * 256 + k], wv, acc[r]);
    }
#pragma unroll
    for (int r = 0; r < 16; r++) fgpart[(size_t)(g0 + r) * 512 + n] = acc[r];
  }
}

// ---------------- layer3 (+stats) / layer3+4+max (OUT=1) ----------------
// LDS: A @0 (64KB) | B @65536 (64KB) | Hl/stats @131072
#define L34S_LDS 133120
#define L34O_LDS 163840
template <int OUT>
__global__ __launch_bounds__(512) void k_l34(const ushort* __restrict__ f2,
                                             const ushort* __restrict__ w3bb,
                                             const ushort* __restrict__ w4b,
                                             const float* __restrict__ fgpart,
                                             const float* __restrict__ bn3,
                                             const float* __restrict__ b4,
                                             float* __restrict__ partials,
                                             float* __restrict__ tokens) {
  extern __shared__ char sm[];
  char* Al = sm;
  char* Bl = sm + 65536;
  char* Hl = sm + 131072;
  float* st = (float*)(sm + 131072);
  const int t = threadIdx.x;
  const int mb = blockIdx.x;
  const size_t R0 = (size_t)mb * 128;
  const int g0 = mb * 4;
  const int l = t & 63, w = t >> 6;
  const int wm = w >> 2, wn = w & 3;   // 2 x 4 waves
  const int lr = l & 15, lh = l >> 4;
  for (int u = t; u < 4096; u += 512) {      // A: f2 tile, async linear-LDS
    int row = u >> 5, c = u & 31;
    gld_lds16((const int4*)(f2 + R0 * 256) + (row * 32 + (c ^ (row & 7))), Al + u * 16);
  }
  facc tacc[4][6];
  if (OUT) {
#pragma unroll
    for (int tm = 0; tm < 4; tm++)
#pragma unroll
      for (int tn = 0; tn < 6; tn++) tacc[tm][tn] = (facc)0.0f;
  }
  for (int kc = 0; kc < 4; kc++) {
    for (int u = t; u < 4096; u += 512) {    // B: w3bb rows [kc*128,+128), async
      int row = u >> 5, c = u & 31;
      gld_lds16((const int4*)(w3bb + (size_t)kc * 128 * 256) + (row * 32 + (c ^ (row & 7))),
                Bl + u * 16);
    }
    __syncthreads();
    facc acc[4][2];
#pragma unroll
    for (int tm = 0; tm < 4; tm++) { acc[tm][0] = (facc)0.0f; acc[tm][1] = (facc)0.0f; }
#pragma unroll
    for (int ks = 0; ks < 8; ks++) {
      const int kb = (ks * 32 + lh * 8) * 2;
      bfrag af[4], bf[2];
#pragma unroll
      for (int tm = 0; tm < 4; tm++) {
        int row = wm * 64 + tm * 16 + lr;
        af[tm] = *(const bfrag*)(Al + row * 512 + (kb ^ ((row & 7) << 4)));
      }
#pragma unroll
      for (int tn = 0; tn < 2; tn++) {
        int rn = wn * 32 + tn * 16 + lr;
        bf[tn] = *(const bfrag*)(Bl + rn * 512 + (kb ^ ((rn & 7) << 4)));
      }
#pragma unroll
      for (int tm = 0; tm < 4; tm++)
#pragma unroll
        for (int tn = 0; tn < 2; tn++)
          acc[tm][tn] = __builtin_amdgcn_mfma_f32_16x16x32_bf16(af[tm], bf[tn], acc[tm][tn], 0, 0, 0);
    }
    float fgp0[2], fgp1[2], a3c[2], s3c[2];
#pragma unroll
    for (int tn = 0; tn < 2; tn++) {
      int col = kc * 128 + wn * 32 + tn * 16 + lr;
      fgp0[tn] = fgpart[(size_t)(g0 + wm * 2) * 512 + col];
      fgp1[tn] = fgpart[(size_t)(g0 + wm * 2 + 1) * 512 + col];
      if (OUT) { a3c[tn] = bn3[col * 2]; s3c[tn] = bn3[col * 2 + 1]; }
    }
    if (OUT == 0) {
      float s1v[2] = {0.f, 0.f}, s2v[2] = {0.f, 0.f};
#pragma unroll
      for (int tm = 0; tm < 4; tm++)
#pragma unroll
        for (int tn = 0; tn < 2; tn++)
#pragma unroll
          for (int r = 0; r < 4; r++) {
            float f3 = acc[tm][tn][r] + (tm < 2 ? fgp0[tn] : fgp1[tn]);
            s1v[tn] += f3; s2v[tn] += f3 * f3;
          }
#pragma unroll
      for (int tn = 0; tn < 2; tn++) {
        s1v[tn] += __shfl_xor(s1v[tn], 16); s1v[tn] += __shfl_xor(s1v[tn], 32);
        s2v[tn] += __shfl_xor(s2v[tn], 16); s2v[tn] += __shfl_xor(s2v[tn], 32);
      }
      if (l < 16) {
#pragma unroll
        for (int tn = 0; tn < 2; tn++) {
          int cl = wn * 32 + tn * 16 + lr;
          st[(wm * 128 + cl) * 2 + 0] = s1v[tn];
          st[(wm * 128 + cl) * 2 + 1] = s2v[tn];
        }
      }
      __syncthreads();
      if (t < 256) {
        int cl = t & 127, s = t >> 7;
        float tot = st[(0 * 128 + cl) * 2 + s] + st[(1 * 128 + cl) * 2 + s];
        partials[(size_t)mb * 1024 + (size_t)(kc * 128 + cl) * 2 + s] = tot;
      }
      __syncthreads();
    } else {
#pragma unroll
      for (int tm = 0; tm < 4; tm++)
#pragma unroll
        for (int tn = 0; tn < 2; tn++)
#pragma unroll
          for (int r = 0; r < 4; r++) {
            int row = wm * 64 + tm * 16 + lh * 4 + r;
            int cl = wn * 32 + tn * 16 + lr;
            float f3 = acc[tm][tn][r] + (tm < 2 ? fgp0[tn] : fgp1[tn]);
            float hv = fmaxf(fmaf(f3, a3c[tn], s3c[tn]), 0.0f);
            *(ushort*)(Hl + row * 256 + ((cl * 2) ^ ((row & 7) << 4))) = f2bf(hv);
          }
      __syncthreads();  // h ready; B free
#pragma unroll
      for (int p = 0; p < 2; p++) {
        for (int u = t; u < 3072; u += 512) {   // w4 piece [384][64] bf16, async
          int row = u >> 3, c = u & 7;
          gld_lds16((const int4*)(w4b + (size_t)row * 512 + kc * 128 + p * 64) + (c ^ (row & 7)),
                    Bl + u * 16);
        }
        __syncthreads();
#pragma unroll
        for (int ks = 0; ks < 2; ks++) {
          const int kbh = (p * 64 + ks * 32 + lh * 8) * 2;
          const int kbb = (ks * 32 + lh * 8) * 2;
          bfrag af[4], bf[6];
#pragma unroll
          for (int tm = 0; tm < 4; tm++) {
            int row = wm * 64 + tm * 16 + lr;
            af[tm] = *(const bfrag*)(Hl + row * 256 + (kbh ^ ((row & 7) << 4)));
          }
#pragma unroll
          for (int tn = 0; tn < 6; tn++) {
            int rn = wn * 96 + tn * 16 + lr;
            bf[tn] = *(const bfrag*)(Bl + rn * 128 + (kbb ^ ((rn & 7) << 4)));
          }
#pragma unroll
          for (int tm = 0; tm < 4; tm++)
#pragma unroll
            for (int tn = 0; tn < 6; tn++)
              tacc[tm][tn] = __builtin_amdgcn_mfma_f32_16x16x32_bf16(af[tm], bf[tn], tacc[tm][tn], 0, 0, 0);
        }
        __syncthreads();
      }
    }
  }
  if (OUT) {
#pragma unroll
    for (int tn = 0; tn < 6; tn++) {
      int col = wn * 96 + tn * 16 + lr;
      float bb = b4[col];
#pragma unroll
      for (int half = 0; half < 2; half++) {
        float mx = -3.4e38f;
#pragma unroll
        for (int tm = half * 2; tm < half * 2 + 2; tm++)
#pragma unroll
          for (int r = 0; r < 4; r++) mx = fmaxf(mx, tacc[tm][tn][r]);
        mx = fmaxf(mx, __shfl_xor(mx, 16));
        mx = fmaxf(mx, __shfl_xor(mx, 32));
        if (l < 16) tokens[(size_t)(g0 + wm * 2 + half) * TDM + col] = mx + bb;
      }
    }
  }
}

// ---------------- BN3 finalize (1024 thr: 8-way chunked sum + LDS reduce) ----------------
__global__ __launch_bounds__(1024) void k_bn3(const float* __restrict__ partials,
                                              const float* __restrict__ g3,
                                              const float* __restrict__ be3,
                                              float* __restrict__ bn3) {
  __shared__ float ls[128][8];
  const int t = threadIdx.x;
  const int slot_l = t & 127;          // slot within this block's 128
  const int chunk = t >> 7;            // 0..7
  const int slot = blockIdx.x * 128 + slot_l;
  float s = 0.f;
  for (int m = chunk * 128; m < chunk * 128 + 128; m++)
    s += partials[(size_t)m * 1024 + slot];
  ls[slot_l][chunk] = s;
  __syncthreads();
  if (t < 64) {
    int col = blockIdx.x * 64 + t;
    float s1 = 0.f, s2 = 0.f;
#pragma unroll
    for (int c = 0; c < 8; c++) { s1 += ls[2 * t][c]; s2 += ls[2 * t + 1][c]; }
    const float rn = 1.0f / (float)NR;
    float mean = s1 * rn;
    float var = s2 * rn - mean * mean;
    float a = g3[col] / sqrtf(var + 1e-5f);
    bn3[col * 2] = a;
    bn3[col * 2 + 1] = be3[col] - mean * a;
  }
}

extern "C" void kernel_launch(void* const* d_in, const int* in_sizes, int n_in,
                              void* d_out, int out_size, void* d_ws, size_t ws_size,
                              hipStream_t stream) {
  const float* points = (const float*)d_in[0];
  const float* w1 = (const float*)d_in[2];
  const float* g1 = (const float*)d_in[3];
  const float* be1 = (const float*)d_in[4];
  const float* w2 = (const float*)d_in[5];
  const float* b2 = (const float*)d_in[6];
  const float* w3 = (const float*)d_in[7];
  const float* g3 = (const float*)d_in[8];
  const float* be3 = (const float*)d_in[9];
  const float* w4 = (const float*)d_in[10];
  const float* b4 = (const float*)d_in[11];
  char* ws = (char*)d_ws;
  int* cidx = (int*)(ws + OFF_CIDX);
  float* centers = (float*)(ws + OFF_CENT);
  float* group = (float*)(ws + OFF_GROUP);
  float* xpart = (float*)(ws + OFF_XPART);
  float* bn1 = (float*)(ws + OFF_BN1);
  float* bn3 = (float*)(ws + OFF_BN3);
  ushort* w2b = (ushort*)(ws + OFF_W2B);
  ushort* w3bb = (ushort*)(ws + OFF_W3BB);
  ushort* w4b = (ushort*)(ws + OFF_W4B);
  float* fg = (float*)(ws + OFF_FG);
  float* fgpart = (float*)(ws + OFF_FGP);
  float* partials = (float*)(ws + OFF_PART);
  ushort* f2 = (ushort*)(ws + OFF_F2);
  float* out = (float*)d_out;
  float* out_centers = out + (size_t)BGT * TDM;
  float* out_mask = out_centers + (size_t)BGT * 3;

  hipFuncSetAttribute((const void*)k_l12, hipFuncAttributeMaxDynamicSharedMemorySize, L12_LDS);
  {
    auto p0 = k_l34<0>; auto p1 = k_l34<1>;
    hipFuncSetAttribute((const void*)p0, hipFuncAttributeMaxDynamicSharedMemorySize, L34S_LDS);
    hipFuncSetAttribute((const void*)p1, hipFuncAttributeMaxDynamicSharedMemorySize, L34O_LDS);
  }

  float* mstate = (float*)(ws + OFF_PART);   // dead until l34<0> writes partials

  // phase 0 carries 712 prep blocks (weight convert + mask) on idle CUs
  k_fps<0><<<NB + 712, 512, 0, stream>>>(points, cidx, centers, out_centers, mstate,
                                         w2, w3, w4, w2b, w3bb, w4b, out_mask);
  k_fps<1><<<NB, 512, 0, stream>>>(points, cidx, centers, out_centers, mstate,
                                   w2, w3, w4, w2b, w3bb, w4b, out_mask);
  k_fps<2><<<NB, 512, 0, stream>>>(points, cidx, centers, out_centers, mstate,
                                   w2, w3, w4, w2b, w3bb, w4b, out_mask);
  k_fps<3><<<NB, 512, 0, stream>>>(points, cidx, centers, out_centers, mstate,
                                   w2, w3, w4, w2b, w3bb, w4b, out_mask);
  k_knn<<<BGT, 512, 0, stream>>>(points, centers, group, xpart);
  k_bn1<<<1, 256, 0, stream>>>(xpart, w1, g1, be1, bn1);
  k_l12<<<NR / 128, 512, L12_LDS, stream>>>(group, w1, bn1, w2b, b2, f2, fg);
  k_fgpart<<<BGT / 16, 256, 0, stream>>>(fg, w3, fgpart);
  k_l34<0><<<NR / 128, 512, L34S_LDS, stream>>>(f2, w3bb, nullptr, fgpart, nullptr, nullptr, partials, nullptr);
  k_bn3<<<8, 1024, 0, stream>>>(partials, g3, be3, bn3);
  k_l34<1><<<NR / 128, 512, L34O_LDS, stream>>>(f2, w3bb, w4b, fgpart, bn3, b4, nullptr, out);
}

// Round 15
// 1093.787 us; speedup vs baseline: 1.2546x; 1.1112x over previous
//
#include <hip/hip_runtime.h>
#include <hip/hip_bf16.h>
#include <cstdint>

#define NB 8
#define NP 16384
#define NG 512
#define NS 32
#define TDM 384
#define BGT (NB*NG)        // 4096 groups total
#define NR (BGT*NS)        // 131072 rows
#define C1 128
#define C2 256
#define C3 512

typedef __attribute__((ext_vector_type(8))) short bfrag;   // 8 bf16
typedef __attribute__((ext_vector_type(4))) float facc;    // 4 f32
typedef __attribute__((ext_vector_type(2))) float f32x2;

__device__ __forceinline__ ushort f2bf(float f) {
  uint32_t u = __float_as_uint(f);
  uint32_t r = (u + 0x7FFFu + ((u >> 16) & 1u)) >> 16;  // RNE
  return (ushort)r;
}
__device__ __forceinline__ float bf2f(ushort h) {
  return __uint_as_float(((uint32_t)h) << 16);
}

// async global->LDS, 16B per lane. LDS dst must be linear in lane order
// (wave-uniform base + lane*16); swizzled layouts are achieved by
// inverse-swizzling the per-lane GLOBAL source (m104/m173 pattern).
__device__ __forceinline__ void gld_lds16(const void* g, void* l) {
  __builtin_amdgcn_global_load_lds(
      (const __attribute__((address_space(1))) void*)g,
      (__attribute__((address_space(3))) void*)l, 16, 0, 0);
}

// ---------------- ws layout (bytes) ----------------
#define OFF_CIDX   0u
#define OFF_CENT   16384u
#define OFF_GROUP  65536u      // 131072*3*4 = 1572864
#define OFF_XPART  1638400u    // 4096*9*4   = 147456
#define OFF_BN1    1785856u    // 128*2*4
#define OFF_BN3    1786880u    // 512*2*4
#define OFF_W2B    1790976u    // 32768*2
#define OFF_W3BB   1856512u    // 131072*2
#define OFF_W4B    2118656u    // 196608*2
#define OFF_FG     2511872u    // 4096*256*4 = 4194304
#define OFF_FGP    6706176u    // 4096*512*4 = 8388608
#define OFF_PART   15094784u   // 1024*1024*4 = 4194304 (also fps m-state: 512KB, dead until l34<0>)
#define OFF_F2     19289088u   // 131072*256*2 = 67108864  -> end 86397952

// ---------------- KNN group body (device fn; shared arrays are per-block) ----------------
// Distances in registers (dl[32]); 4-way sub-banked histograms; parallel bin
// search; rank-select (exact same selected SET as iterative lex-min).
__device__ __forceinline__ unsigned wave_iscan(unsigned v, int lane) {
#pragma unroll
  for (int s = 1; s < 64; s <<= 1) {
    unsigned o = (unsigned)__shfl_up((int)v, s);
    if (lane >= s) v += o;
  }
  return v;
}

__device__ void knn_group(int bg, const float* __restrict__ pts,
                          const float* __restrict__ centers,
                          float* __restrict__ group,
                          float* __restrict__ xpart) {
  __shared__ uint32_t h1[4][257];
  __shared__ uint32_t h2[4][257];
  __shared__ int cand_i[1024];
  __shared__ float cand_v[1024];
  __shared__ int sel[32];
  __shared__ float selc[96];
  __shared__ unsigned wsum[4];
  __shared__ int cnts[8];
  __shared__ float redv[8];
  __shared__ int redi[8];
  const int t = threadIdx.x;
  const int lane = t & 63;
  const int cp = lane & 3;
  const int b = bg >> 9;
  const float* P = pts + (size_t)b * NP * 3;
  const float cx = centers[bg * 3], cy = centers[bg * 3 + 1], cz = centers[bg * 3 + 2];
  float dl[32];
#pragma unroll
  for (int rr = 0; rr < NP / 512; rr++) {
    int p = rr * 512 + t;
    float dx = __fsub_rn(P[p * 3], cx);
    float dy = __fsub_rn(P[p * 3 + 1], cy);
    float dz = __fsub_rn(P[p * 3 + 2], cz);
    dl[rr] = __fadd_rn(__fadd_rn(__fmul_rn(dx, dx), __fmul_rn(dy, dy)), __fmul_rn(dz, dz));
  }
  for (int u = t; u < 4 * 257; u += 512) { h1[0][u] = 0; h2[0][u] = 0; }  // flat zero both
  if (t < 8) cnts[t] = 0;
  __syncthreads();
#pragma unroll
  for (int rr = 0; rr < NP / 512; rr++)
    atomicAdd(&h1[cp][__float_as_uint(dl[rr]) >> 23], 1u);
  __syncthreads();
  // parallel bin search on h1 (sum of 4 copies per bin)
  unsigned v1 = 0, i1 = 0;
  if (t < 256) {
    v1 = h1[0][t] + h1[1][t] + h1[2][t] + h1[3][t];
    i1 = wave_iscan(v1, lane);
    if (lane == 63) wsum[t >> 6] = i1;
  }
  __syncthreads();
  if (t < 256) {
    unsigned off = 0;
    for (int q = 0; q < (t >> 6); q++) off += wsum[q];
    unsigned incl = i1 + off, excl = incl - v1;
    if (incl >= NS && excl < NS) { cnts[2] = t; cnts[3] = (int)excl; }
  }
  __syncthreads();
  const uint32_t e1 = (uint32_t)cnts[2];
  const int lt0 = cnts[3];
#pragma unroll
  for (int rr = 0; rr < NP / 512; rr++) {
    uint32_t bits = __float_as_uint(dl[rr]);
    if ((bits >> 23) == e1) atomicAdd(&h2[cp][(bits >> 15) & 255u], 1u);
  }
  __syncthreads();
  unsigned v2 = 0, i2 = 0;
  if (t < 256) {
    v2 = h2[0][t] + h2[1][t] + h2[2][t] + h2[3][t];
    i2 = wave_iscan(v2, lane);
    if (lane == 63) wsum[t >> 6] = i2;
  }
  __syncthreads();
  if (t < 256) {
    unsigned off = 0;
    for (int q = 0; q < (t >> 6); q++) off += wsum[q];
    unsigned incl = (unsigned)lt0 + i2 + off, excl = incl - v2;
    if (incl >= NS && excl < NS) { cnts[4] = t; cnts[5] = (int)excl; }
  }
  __syncthreads();
  const uint32_t keystar = (e1 << 8) | (uint32_t)cnts[4];
  const int lt = cnts[5];            // strictly-below count, < 32
#pragma unroll
  for (int rr = 0; rr < NP / 512; rr++) {
    int p = rr * 512 + t;
    uint32_t key = __float_as_uint(dl[rr]) >> 15;
    if (key < keystar) { int pos = atomicAdd(&cnts[0], 1); sel[pos] = p; }
    else if (key == keystar) {
      int pos = atomicAdd(&cnts[1], 1);
      if (pos < 1024) { cand_i[pos] = p; cand_v[pos] = dl[rr]; }
    }
  }
  __syncthreads();
  const int neq = cnts[1];
  if (neq <= 1024) {
    // rank-select: one pass (typ. neq << 100)
    const int need = NS - lt;
    for (int e = t; e < neq; e += 512) {
      int p = cand_i[e];
      float v = cand_v[e];
      int rank = 0;
      for (int q = 0; q < neq; q++) {
        int pq = cand_i[q];                 // broadcast LDS reads
        float vq = cand_v[q];
        rank += (vq < v || (vq == v && pq < p)) ? 1 : 0;
      }
      if (rank < need) sel[lt + rank] = p;
    }
    __syncthreads();
  } else {
    // overflow fallback (rare): register-based iterative lex-min extraction
    uint32_t taken = 0;
    for (int j = 0; j < NS; j++) {
      float bv = 3.4e38f; int bp = 0x7FFFFFFF;
#pragma unroll
      for (int rr = 0; rr < NP / 512; rr++) {
        if (!((taken >> rr) & 1u)) {
          float v = dl[rr];
          int p = rr * 512 + t;
          if (v < bv || (v == bv && p < bp)) { bv = v; bp = p; }
        }
      }
#pragma unroll
      for (int off = 32; off >= 1; off >>= 1) {
        float ov = __shfl_xor(bv, off);
        int   op = __shfl_xor(bp, off);
        if (ov < bv || (ov == bv && op < bp)) { bv = ov; bp = op; }
      }
      if (lane == 0) { redv[t >> 6] = bv; redi[t >> 6] = bp; }
      __syncthreads();
      float fv = redv[0]; int fp = redi[0];
      for (int q = 1; q < 8; q++)
        if (redv[q] < fv || (redv[q] == fv && redi[q] < fp)) { fv = redv[q]; fp = redi[q]; }
      if (t == (fp & 511)) taken |= 1u << (fp >> 9);
      if (t == 0) sel[j] = fp;
      __syncthreads();
    }
  }
  if (t < NS) {
    int p = sel[t];
    float gx = __fsub_rn(P[p * 3], cx);
    float gy = __fsub_rn(P[p * 3 + 1], cy);
    float gz = __fsub_rn(P[p * 3 + 2], cz);
    size_t row = ((size_t)bg * NS + t) * 3;
    group[row] = gx; group[row + 1] = gy; group[row + 2] = gz;
    selc[t * 3] = gx; selc[t * 3 + 1] = gy; selc[t * 3 + 2] = gz;
  }
  __syncthreads();
  if (t < 32) {   // parallel x-stats: one row each, 5-step xor-reduce (lanes 0..31)
    float x = selc[t * 3], y = selc[t * 3 + 1], z = selc[t * 3 + 2];
    float s0 = x, s1 = y, s2 = z;
    float s3 = x * x, s4 = y * y, s5 = z * z;
    float s6 = x * y, s7 = x * z, s8 = y * z;
#pragma unroll
    for (int off = 16; off >= 1; off >>= 1) {
      s0 += __shfl_xor(s0, off); s1 += __shfl_xor(s1, off); s2 += __shfl_xor(s2, off);
      s3 += __shfl_xor(s3, off); s4 += __shfl_xor(s4, off); s5 += __shfl_xor(s5, off);
      s6 += __shfl_xor(s6, off); s7 += __shfl_xor(s7, off); s8 += __shfl_xor(s8, off);
    }
    if (t == 0) {
      float* xp = xpart + (size_t)bg * 9;
      xp[0]=s0; xp[1]=s1; xp[2]=s2; xp[3]=s3; xp[4]=s4; xp[5]=s5; xp[6]=s6; xp[7]=s7; xp[8]=s8;
    }
  }
}

// ---------------- FPS (4 phases of 128 iters) + prep/knn folded in ----------------
// Phase 0 carries 712 prep blocks; phases 1-3 each carry 1024 knn blocks for
// the center chunk produced by the PREVIOUS phase (stream-order visible).
// Launched with an 80KB dynamic-LDS pad -> 1 block/CU, so the 8 fps blocks
// (dispatched first, critical path) never share a CU with knn blocks.
template <int PHASE>
__global__ __launch_bounds__(512, 2) void k_fps(const float* __restrict__ pts,
                                                int* __restrict__ cidx,
                                                float* __restrict__ centers,
                                                float* __restrict__ outc,
                                                float* __restrict__ mstate,
                                                const float* __restrict__ w2,
                                                const float* __restrict__ w3,
                                                const float* __restrict__ w4,
                                                ushort* __restrict__ w2b,
                                                ushort* __restrict__ w3bb,
                                                ushort* __restrict__ w4b,
                                                float* __restrict__ mask,
                                                float* __restrict__ group,
                                                float* __restrict__ xpart) {
#pragma clang fp contract(off)
  const int t = threadIdx.x;
  if (PHASE == 0 && blockIdx.x >= NB) {      // prep blocks (idle CUs)
    int i = (blockIdx.x - NB) * 512 + t;
    if (i < 32768) {
      int r = i >> 7, c = i & 127;
      w2b[i] = f2bf(w2[r * 128 + c]);
    } else if (i < 163840) {
      int j = i - 32768; int r = j >> 8, c = j & 255;
      w3bb[j] = f2bf(w3[(size_t)r * 512 + 256 + c]);
    } else if (i < 360448) {
      int j = i - 163840; int r = j >> 9, c = j & 511;
      w4b[j] = f2bf(w4[(size_t)r * 512 + c]);
    } else if (i < 364544) {
      mask[i - 360448] = 1.0f;
    }
    return;
  }
  if (PHASE >= 1 && blockIdx.x >= NB) {      // knn blocks: chunk PHASE-1
    int j = blockIdx.x - NB;
    int b = j >> 7;
    int gi = (PHASE - 1) * 128 + (j & 127);
    knn_group(b * NG + gi, pts, centers, group, xpart);
    return;
  }
  const int b = blockIdx.x;
  const float* P = pts + (size_t)b * NP * 3;
  f32x2 px[16], py[16], pz[16], m[16];
#pragma unroll
  for (int k = 0; k < 16; k++) {
    int p0 = (2 * k) * 512 + t;
    int p1 = p0 + 512;
    px[k] = (f32x2){P[p0 * 3 + 0], P[p1 * 3 + 0]};
    py[k] = (f32x2){P[p0 * 3 + 1], P[p1 * 3 + 1]};
    pz[k] = (f32x2){P[p0 * 3 + 2], P[p1 * 3 + 2]};
    if (PHASE == 0) {
      m[k] = (f32x2){1e10f, 1e10f};
    } else {
      m[k].x = mstate[(size_t)(b * 32 + 2 * k) * 512 + t];
      m[k].y = mstate[(size_t)(b * 32 + 2 * k + 1) * 512 + t];
    }
  }
  __shared__ double kb[2][8];
  float cx, cy, cz;
  if (PHASE == 0) {
    cx = P[0]; cy = P[1]; cz = P[2];
    if (t == 0) {
      cidx[b * NG] = 0;
      size_t o = (size_t)b * NG * 3;
      centers[o] = cx; centers[o + 1] = cy; centers[o + 2] = cz;
      outc[o] = cx; outc[o + 1] = cy; outc[o + 2] = cz;
    }
  } else {
    size_t o = ((size_t)b * NG + (PHASE * 128 - 1)) * 3;
    cx = centers[o]; cy = centers[o + 1]; cz = centers[o + 2];
  }
  const unsigned nt = ~(unsigned)t;
  const int i_beg = (PHASE == 0) ? 1 : PHASE * 128;
  const int i_end = (PHASE + 1) * 128;
  for (int i = i_beg; i < i_end; i++) {
    const int par = i & 1;
    const f32x2 ccx = (f32x2){cx, cx};
    const f32x2 ccy = (f32x2){cy, cy};
    const f32x2 ccz = (f32x2){cz, cz};
    double A = 0.0, B = 0.0;   // 2 independent 8-deep max chains
#pragma unroll
    for (int k = 0; k < 16; k++) {
      // exact reference arithmetic: sub, mul, (x2+y2)+z2, no fma (contract off)
      f32x2 dx = px[k] - ccx;
      f32x2 dy = py[k] - ccy;
      f32x2 dz = pz[k] - ccz;
      f32x2 d = (dx * dx + dy * dy) + dz * dz;
      f32x2 mm = __builtin_elementwise_min(m[k], d);
      m[k] = mm;
      unsigned lo0 = nt - (unsigned)(2 * k) * 512u;       // == ~(p0)
      unsigned lo1 = nt - (unsigned)(2 * k + 1) * 512u;   // == ~(p1)
      double k0 = __longlong_as_double(((unsigned long long)__float_as_uint(mm.x) << 32) | lo0);
      double k1 = __longlong_as_double(((unsigned long long)__float_as_uint(mm.y) << 32) | lo1);
      A = fmax(A, k0);
      B = fmax(B, k1);
    }
    double best = fmax(A, B);
#pragma unroll
    for (int off = 1; off < 64; off <<= 1)
      best = fmax(best, __shfl_xor(best, off));
    if ((t & 63) == 0) kb[par][t >> 6] = best;
    __syncthreads();
    double v0 = fmax(kb[par][0], kb[par][1]);
    double v1 = fmax(kb[par][2], kb[par][3]);
    double v2 = fmax(kb[par][4], kb[par][5]);
    double v3 = fmax(kb[par][6], kb[par][7]);
    const double g = fmax(fmax(v0, v1), fmax(v2, v3));
    const int gidx = (int)(~(unsigned)__double_as_longlong(g));
    const float* q = P + (size_t)gidx * 3;
    cx = q[0]; cy = q[1]; cz = q[2];
    if (t == 0) {
      cidx[b * NG + i] = gidx;
      size_t o = ((size_t)b * NG + i) * 3;
      centers[o] = cx; centers[o + 1] = cy; centers[o + 2] = cz;
      outc[o] = cx; outc[o + 1] = cy; outc[o + 2] = cz;
    }
  }
  if (PHASE < 3) {
#pragma unroll
    for (int k = 0; k < 16; k++) {
      mstate[(size_t)(b * 32 + 2 * k) * 512 + t] = m[k].x;
      mstate[(size_t)(b * 32 + 2 * k + 1) * 512 + t] = m[k].y;
    }
  }
}

// ---------------- KNN standalone: final chunk [384,512) ----------------
__global__ __launch_bounds__(512) void k_knn(const float* __restrict__ pts,
                                             const float* __restrict__ centers,
                                             float* __restrict__ group,
                                             float* __restrict__ xpart,
                                             int gbase) {
  int j = blockIdx.x;
  int b = j >> 7;
  int gi = gbase + (j & 127);
  knn_group(b * NG + gi, pts, centers, group, xpart);
}

// ---------------- BN1 from analytic moments ----------------
__global__ __launch_bounds__(256) void k_bn1(const float* __restrict__ xpart,
                                             const float* __restrict__ w1,
                                             const float* __restrict__ g1,
                                             const float* __restrict__ be1,
                                             float* __restrict__ bn1) {
  __shared__ float wsum[4][9];
  __shared__ float S[9];
  const int t = threadIdx.x;
  float s[9];
#pragma unroll
  for (int j = 0; j < 9; j++) s[j] = 0.f;
  for (int i = t; i < BGT; i += 256) {
    const float* xp = xpart + (size_t)i * 9;
#pragma unroll
    for (int j = 0; j < 9; j++) s[j] += xp[j];
  }
#pragma unroll
  for (int off = 32; off >= 1; off >>= 1)
#pragma unroll
    for (int j = 0; j < 9; j++) s[j] += __shfl_xor(s[j], off);
  if ((t & 63) == 0)
#pragma unroll
    for (int j = 0; j < 9; j++) wsum[t >> 6][j] = s[j];
  __syncthreads();
  if (t == 0)
#pragma unroll
    for (int j = 0; j < 9; j++) S[j] = wsum[0][j] + wsum[1][j] + wsum[2][j] + wsum[3][j];
  __syncthreads();
  if (t < C1) {
    const float rn = 1.0f / (float)NR;
    float ex = S[0]*rn, ey = S[1]*rn, ez = S[2]*rn;
    float exx = S[3]*rn, eyy = S[4]*rn, ezz = S[5]*rn;
    float exy = S[6]*rn, exz = S[7]*rn, eyz = S[8]*rn;
    float a = w1[t*3], b = w1[t*3+1], c = w1[t*3+2];
    float mean = a*ex + b*ey + c*ez;
    float e2 = a*a*exx + b*b*eyy + c*c*ezz + 2.f*(a*b*exy + a*c*exz + b*c*eyz);
    float var = e2 - mean*mean;
    float sc = g1[t] / sqrtf(var + 1e-5f);
    bn1[t*2] = sc;
    bn1[t*2+1] = be1[t] - mean*sc;
  }
}

// ---------------- layer1+2 fused GEMM + fg ----------------
// LDS: xr @0 | a1s1 @1536 | f1A @4096 (32KB) | w2B @36864 (64KB) | f2s @4096 (64KB, reuse)
#define L12_LDS 102400
__global__ __launch_bounds__(512) void k_l12(const float* __restrict__ group,
                                             const float* __restrict__ w1,
                                             const float* __restrict__ bn1,
                                             const ushort* __restrict__ w2b,
                                             const float* __restrict__ b2,
                                             ushort* __restrict__ f2,
                                             float* __restrict__ fg) {
  extern __shared__ char sm[];
  float* xr = (float*)sm;
  float* a1s1 = (float*)(sm + 1536);
  char* f1A = sm + 4096;
  char* w2B = sm + 36864;
  char* f2s = sm + 4096;
  const int t = threadIdx.x;
  const int mb = blockIdx.x;
  const size_t R0 = (size_t)mb * 128;
  if (t < 384) xr[t] = group[R0 * 3 + t];
  if (t < 256) a1s1[t] = bn1[t];
  for (int u = t; u < 4096; u += 512) {      // w2 [256][128] bf16: async, linear LDS,
    int row = u >> 4, c = u & 15;            // inverse-swizzled global src
    gld_lds16((const int4*)w2b + (row * 16 + (c ^ (row & 7))), w2B + u * 16);
  }
  __syncthreads();
  {
    const int c = t & 127;
    const int rb = t >> 7;
    const float wa = w1[c*3], wb = w1[c*3+1], wc = w1[c*3+2];
    const float a1 = a1s1[c*2], s1 = a1s1[c*2+1];
#pragma unroll 4
    for (int i = 0; i < 32; i++) {
      int r = rb * 32 + i;
      float f = xr[r*3] * wa + xr[r*3+1] * wb + xr[r*3+2] * wc;
      float h = fmaxf(fmaf(f, a1, s1), 0.0f);
      *(ushort*)(f1A + r * 256 + ((c * 2) ^ ((r & 7) << 4))) = f2bf(h);
    }
  }
  __syncthreads();
  const int l = t & 63, w = t >> 6;
  const int wm = w >> 2, wn = w & 3;   // 2 x 4 waves, wave tile 64x64
  const int lr = l & 15, lh = l >> 4;
  facc acc[4][4];
#pragma unroll
  for (int tm = 0; tm < 4; tm++)
#pragma unroll
    for (int tn = 0; tn < 4; tn++) acc[tm][tn] = (facc)0.0f;
#pragma unroll
  for (int ks = 0; ks < 4; ks++) {
    const int kb = (ks * 32 + lh * 8) * 2;
    bfrag af[4], bf[4];
#pragma unroll
    for (int tm = 0; tm < 4; tm++) {
      int row = wm * 64 + tm * 16 + lr;
      af[tm] = *(const bfrag*)(f1A + row * 256 + (kb ^ ((row & 7) << 4)));
    }
#pragma unroll
    for (int tn = 0; tn < 4; tn++) {
      int rn = wn * 64 + tn * 16 + lr;
      bf[tn] = *(const bfrag*)(w2B + rn * 256 + (kb ^ ((rn & 7) << 4)));
    }
#pragma unroll
    for (int tm = 0; tm < 4; tm++)
#pragma unroll
      for (int tn = 0; tn < 4; tn++)
        acc[tm][tn] = __builtin_amdgcn_mfma_f32_16x16x32_bf16(af[tm], bf[tn], acc[tm][tn], 0, 0, 0);
  }
  __syncthreads();   // before reusing region as f2s
#pragma unroll
  for (int tn = 0; tn < 4; tn++) {
    int col = wn * 64 + tn * 16 + lr;
    float bb = b2[col];
#pragma unroll
    for (int tm = 0; tm < 4; tm++)
#pragma unroll
      for (int r = 0; r < 4; r++) {
        int row = wm * 64 + tm * 16 + lh * 4 + r;
        *(ushort*)(f2s + row * 512 + ((col * 2) ^ ((row & 7) << 4))) = f2bf(acc[tm][tn][r] + bb);
      }
  }
  __syncthreads();
  for (int u = t; u < 4096; u += 512) {      // f2 tile -> global, [128][256] bf16
    int row = u >> 5, cu = u & 31;
    int4 v = *(const int4*)(f2s + row * 512 + ((cu * 16) ^ ((row & 7) << 4)));
    ((int4*)(f2 + R0 * 256))[u] = v;
  }
  for (int task = t; task < 1024; task += 512) {
    int g = task >> 8, c = task & 255;
    float mx = -3.4e38f;
#pragma unroll 8
    for (int r = 0; r < 32; r++) {
      int row = g * 32 + r;
      mx = fmaxf(mx, bf2f(*(const ushort*)(f2s + row * 512 + ((c * 2) ^ ((row & 7) << 4)))));
    }
    fg[(size_t)(mb * 4 + g) * 256 + c] = mx;
  }
}

// ---------------- fgpart = fg @ w3[:, :256]^T (f32) ----------------
__global__ __launch_bounds__(256) void k_fgpart(const float* __restrict__ fg,
                                                const float* __restrict__ w3,
                                                float* __restrict__ fgpart) {
  __shared__ float fgs[16 * 256];
  const int t = threadIdx.x;
  const int g0 = blockIdx.x * 16;
  for (int i = t; i < 4096; i += 256) fgs[i] = fg[(size_t)g0 * 256 + i];
  __syncthreads();
  for (int half = 0; half < 2; half++) {
    int n = half * 256 + t;
    const float* wr = w3 + (size_t)n * 512;
    float acc[16];
#pragma unroll
    for (int r = 0; r < 16; r++) acc[r] = 0.f;
    for (int k = 0; k < 256; k++) {
      float wv = wr[k];
#pragma unroll
      for (int r = 0; r < 16; r++) acc[r] = fmaf(fgs[r * 256 + k], wv, acc[r]);
    }
#pragma unroll
    for (int r = 0; r < 16; r++) fgpart[(size_t)(g0 + r) * 512 + n] = acc[r];
  }
}

// ---------------- layer3 (+stats) / layer3+4+max (OUT=1) ----------------
// LDS: A @0 (64KB) | B @65536 (64KB) | Hl/stats @131072
#define L34S_LDS 133120
#define L34O_LDS 163840
template <int OUT>
__global__ __launch_bounds__(512) void k_l34(const ushort* __restrict__ f2,
                                             const ushort* __restrict__ w3bb,
                                             const ushort* __restrict__ w4b,
                                             const float* __restrict__ fgpart,
                                             const float* __restrict__ bn3,
                                             const float* __restrict__ b4,
                                             float* __restrict__ partials,
                                             float* __restrict__ tokens) {
  extern __shared__ char sm[];
  char* Al = sm;
  char* Bl = sm + 65536;
  char* Hl = sm + 131072;
  float* st = (float*)(sm + 131072);
  const int t = threadIdx.x;
  const int mb = blockIdx.x;
  const size_t R0 = (size_t)mb * 128;
  const int g0 = mb * 4;
  const int l = t & 63, w = t >> 6;
  const int wm = w >> 2, wn = w & 3;   // 2 x 4 waves
  const int lr = l & 15, lh = l >> 4;
  for (int u = t; u < 4096; u += 512) {      // A: f2 tile, async linear-LDS
    int row = u >> 5, c = u & 31;
    gld_lds16((const int4*)(f2 + R0 * 256) + (row * 32 + (c ^ (row & 7))), Al + u * 16);
  }
  facc tacc[4][6];
  if (OUT) {
#pragma unroll
    for (int tm = 0; tm < 4; tm++)
#pragma unroll
      for (int tn = 0; tn < 6; tn++) tacc[tm][tn] = (facc)0.0f;
  }
  for (int kc = 0; kc < 4; kc++) {
    for (int u = t; u < 4096; u += 512) {    // B: w3bb rows [kc*128,+128), async
      int row = u >> 5, c = u & 31;
      gld_lds16((const int4*)(w3bb + (size_t)kc * 128 * 256) + (row * 32 + (c ^ (row & 7))),
                Bl + u * 16);
    }
    __syncthreads();
    facc acc[4][2];
#pragma unroll
    for (int tm = 0; tm < 4; tm++) { acc[tm][0] = (facc)0.0f; acc[tm][1] = (facc)0.0f; }
#pragma unroll
    for (int ks = 0; ks < 8; ks++) {
      const int kb = (ks * 32 + lh * 8) * 2;
      bfrag af[4], bf[2];
#pragma unroll
      for (int tm = 0; tm < 4; tm++) {
        int row = wm * 64 + tm * 16 + lr;
        af[tm] = *(const bfrag*)(Al + row * 512 + (kb ^ ((row & 7) << 4)));
      }
#pragma unroll
      for (int tn = 0; tn < 2; tn++) {
        int rn = wn * 32 + tn * 16 + lr;
        bf[tn] = *(const bfrag*)(Bl + rn * 512 + (kb ^ ((rn & 7) << 4)));
      }
#pragma unroll
      for (int tm = 0; tm < 4; tm++)
#pragma unroll
        for (int tn = 0; tn < 2; tn++)
          acc[tm][tn] = __builtin_amdgcn_mfma_f32_16x16x32_bf16(af[tm], bf[tn], acc[tm][tn], 0, 0, 0);
    }
    float fgp0[2], fgp1[2], a3c[2], s3c[2];
#pragma unroll
    for (int tn = 0; tn < 2; tn++) {
      int col = kc * 128 + wn * 32 + tn * 16 + lr;
      fgp0[tn] = fgpart[(size_t)(g0 + wm * 2) * 512 + col];
      fgp1[tn] = fgpart[(size_t)(g0 + wm * 2 + 1) * 512 + col];
      if (OUT) { a3c[tn] = bn3[col * 2]; s3c[tn] = bn3[col * 2 + 1]; }
    }
    if (OUT == 0) {
      float s1v[2] = {0.f, 0.f}, s2v[2] = {0.f, 0.f};
#pragma unroll
      for (int tm = 0; tm < 4; tm++)
#pragma unroll
        for (int tn = 0; tn < 2; tn++)
#pragma unroll
          for (int r = 0; r < 4; r++) {
            float f3 = acc[tm][tn][r] + (tm < 2 ? fgp0[tn] : fgp1[tn]);
            s1v[tn] += f3; s2v[tn] += f3 * f3;
          }
#pragma unroll
      for (int tn = 0; tn < 2; tn++) {
        s1v[tn] += __shfl_xor(s1v[tn], 16); s1v[tn] += __shfl_xor(s1v[tn], 32);
        s2v[tn] += __shfl_xor(s2v[tn], 16); s2v[tn] += __shfl_xor(s2v[tn], 32);
      }
      if (l < 16) {
#pragma unroll
        for (int tn = 0; tn < 2; tn++) {
          int cl = wn * 32 + tn * 16 + lr;
          st[(wm * 128 + cl) * 2 + 0] = s1v[tn];
          st[(wm * 128 + cl) * 2 + 1] = s2v[tn];
        }
      }
      __syncthreads();
      if (t < 256) {
        int cl = t & 127, s = t >> 7;
        float tot = st[(0 * 128 + cl) * 2 + s] + st[(1 * 128 + cl) * 2 + s];
        partials[(size_t)mb * 1024 + (size_t)(kc * 128 + cl) * 2 + s] = tot;
      }
      __syncthreads();
    } else {
#pragma unroll
      for (int tm = 0; tm < 4; tm++)
#pragma unroll
        for (int tn = 0; tn < 2; tn++)
#pragma unroll
          for (int r = 0; r < 4; r++) {
            int row = wm * 64 + tm * 16 + lh * 4 + r;
            int cl = wn * 32 + tn * 16 + lr;
            float f3 = acc[tm][tn][r] + (tm < 2 ? fgp0[tn] : fgp1[tn]);
            float hv = fmaxf(fmaf(f3, a3c[tn], s3c[tn]), 0.0f);
            *(ushort*)(Hl + row * 256 + ((cl * 2) ^ ((row & 7) << 4))) = f2bf(hv);
          }
      __syncthreads();  // h ready; B free
#pragma unroll
      for (int p = 0; p < 2; p++) {
        for (int u = t; u < 3072; u += 512) {   // w4 piece [384][64] bf16, async
          int row = u >> 3, c = u & 7;
          gld_lds16((const int4*)(w4b + (size_t)row * 512 + kc * 128 + p * 64) + (c ^ (row & 7)),
                    Bl + u * 16);
        }
        __syncthreads();
#pragma unroll
        for (int ks = 0; ks < 2; ks++) {
          const int kbh = (p * 64 + ks * 32 + lh * 8) * 2;
          const int kbb = (ks * 32 + lh * 8) * 2;
          bfrag af[4], bf[6];
#pragma unroll
          for (int tm = 0; tm < 4; tm++) {
            int row = wm * 64 + tm * 16 + lr;
            af[tm] = *(const bfrag*)(Hl + row * 256 + (kbh ^ ((row & 7) << 4)));
          }
#pragma unroll
          for (int tn = 0; tn < 6; tn++) {
            int rn = wn * 96 + tn * 16 + lr;
            bf[tn] = *(const bfrag*)(Bl + rn * 128 + (kbb ^ ((rn & 7) << 4)));
          }
#pragma unroll
          for (int tm = 0; tm < 4; tm++)
#pragma unroll
            for (int tn = 0; tn < 6; tn++)
              tacc[tm][tn] = __builtin_amdgcn_mfma_f32_16x16x32_bf16(af[tm], bf[tn], tacc[tm][tn], 0, 0, 0);
        }
        __syncthreads();
      }
    }
  }
  if (OUT) {
#pragma unroll
    for (int tn = 0; tn < 6; tn++) {
      int col = wn * 96 + tn * 16 + lr;
      float bb = b4[col];
#pragma unroll
      for (int half = 0; half < 2; half++) {
        float mx = -3.4e38f;
#pragma unroll
        for (int tm = half * 2; tm < half * 2 + 2; tm++)
#pragma unroll
          for (int r = 0; r < 4; r++) mx = fmaxf(mx, tacc[tm][tn][r]);
        mx = fmaxf(mx, __shfl_xor(mx, 16));
        mx = fmaxf(mx, __shfl_xor(mx, 32));
        if (l < 16) tokens[(size_t)(g0 + wm * 2 + half) * TDM + col] = mx + bb;
      }
    }
  }
}

// ---------------- BN3 finalize (1024 thr: 8-way chunked sum + LDS reduce) ----------------
__global__ __launch_bounds__(1024) void k_bn3(const float* __restrict__ partials,
                                              const float* __restrict__ g3,
                                              const float* __restrict__ be3,
                                              float* __restrict__ bn3) {
  __shared__ float ls[128][8];
  const int t = threadIdx.x;
  const int slot_l = t & 127;          // slot within this block's 128
  const int chunk = t >> 7;            // 0..7
  const int slot = blockIdx.x * 128 + slot_l;
  float s = 0.f;
  for (int m = chunk * 128; m < chunk * 128 + 128; m++)
    s += partials[(size_t)m * 1024 + slot];
  ls[slot_l][chunk] = s;
  __syncthreads();
  if (t < 64) {
    int col = blockIdx.x * 64 + t;
    float s1 = 0.f, s2 = 0.f;
#pragma unroll
    for (int c = 0; c < 8; c++) { s1 += ls[2 * t][c]; s2 += ls[2 * t + 1][c]; }
    const float rn = 1.0f / (float)NR;
    float mean = s1 * rn;
    float var = s2 * rn - mean * mean;
    float a = g3[col] / sqrtf(var + 1e-5f);
    bn3[col * 2] = a;
    bn3[col * 2 + 1] = be3[col] - mean * a;
  }
}

#define FPS_PAD 81920   // dynamic-LDS pad -> 1 block/CU in merged fps kernels

extern "C" void kernel_launch(void* const* d_in, const int* in_sizes, int n_in,
                              void* d_out, int out_size, void* d_ws, size_t ws_size,
                              hipStream_t stream) {
  const float* points = (const float*)d_in[0];
  const float* w1 = (const float*)d_in[2];
  const float* g1 = (const float*)d_in[3];
  const float* be1 = (const float*)d_in[4];
  const float* w2 = (const float*)d_in[5];
  const float* b2 = (const float*)d_in[6];
  const float* w3 = (const float*)d_in[7];
  const float* g3 = (const float*)d_in[8];
  const float* be3 = (const float*)d_in[9];
  const float* w4 = (const float*)d_in[10];
  const float* b4 = (const float*)d_in[11];
  char* ws = (char*)d_ws;
  int* cidx = (int*)(ws + OFF_CIDX);
  float* centers = (float*)(ws + OFF_CENT);
  float* group = (float*)(ws + OFF_GROUP);
  float* xpart = (float*)(ws + OFF_XPART);
  float* bn1 = (float*)(ws + OFF_BN1);
  float* bn3 = (float*)(ws + OFF_BN3);
  ushort* w2b = (ushort*)(ws + OFF_W2B);
  ushort* w3bb = (ushort*)(ws + OFF_W3BB);
  ushort* w4b = (ushort*)(ws + OFF_W4B);
  float* fg = (float*)(ws + OFF_FG);
  float* fgpart = (float*)(ws + OFF_FGP);
  float* partials = (float*)(ws + OFF_PART);
  ushort* f2 = (ushort*)(ws + OFF_F2);
  float* out = (float*)d_out;
  float* out_centers = out + (size_t)BGT * TDM;
  float* out_mask = out_centers + (size_t)BGT * 3;

  hipFuncSetAttribute((const void*)k_l12, hipFuncAttributeMaxDynamicSharedMemorySize, L12_LDS);
  {
    auto p0 = k_l34<0>; auto p1 = k_l34<1>;
    hipFuncSetAttribute((const void*)p0, hipFuncAttributeMaxDynamicSharedMemorySize, L34S_LDS);
    hipFuncSetAttribute((const void*)p1, hipFuncAttributeMaxDynamicSharedMemorySize, L34O_LDS);
  }
  {
    auto f0 = k_fps<0>; auto f1 = k_fps<1>; auto f2k = k_fps<2>; auto f3 = k_fps<3>;
    hipFuncSetAttribute((const void*)f0, hipFuncAttributeMaxDynamicSharedMemorySize, FPS_PAD);
    hipFuncSetAttribute((const void*)f1, hipFuncAttributeMaxDynamicSharedMemorySize, FPS_PAD);
    hipFuncSetAttribute((const void*)f2k, hipFuncAttributeMaxDynamicSharedMemorySize, FPS_PAD);
    hipFuncSetAttribute((const void*)f3, hipFuncAttributeMaxDynamicSharedMemorySize, FPS_PAD);
  }

  float* mstate = (float*)(ws + OFF_PART);   // dead until l34<0> writes partials

  // phase 0 carries prep; phases 1-3 each carry the 1024-block knn chunk for
  // the centers the PREVIOUS phase produced; 80KB dyn pad -> fps blocks get
  // exclusive CUs (knn/prep blocks run 1/CU on the other 248 CUs, hidden).
  k_fps<0><<<NB + 712, 512, FPS_PAD, stream>>>(points, cidx, centers, out_centers, mstate,
                                               w2, w3, w4, w2b, w3bb, w4b, out_mask, group, xpart);
  k_fps<1><<<NB + 1024, 512, FPS_PAD, stream>>>(points, cidx, centers, out_centers, mstate,
                                                w2, w3, w4, w2b, w3bb, w4b, out_mask, group, xpart);
  k_fps<2><<<NB + 1024, 512, FPS_PAD, stream>>>(points, cidx, centers, out_centers, mstate,
                                                w2, w3, w4, w2b, w3bb, w4b, out_mask, group, xpart);
  k_fps<3><<<NB + 1024, 512, FPS_PAD, stream>>>(points, cidx, centers, out_centers, mstate,
                                                w2, w3, w4, w2b, w3bb, w4b, out_mask, group, xpart);
  k_knn<<<1024, 512, 0, stream>>>(points, centers, group, xpart, 384);
  k_bn1<<<1, 256, 0, stream>>>(xpart, w1, g1, be1, bn1);
  k_l12<<<NR / 128, 512, L12_LDS, stream>>>(group, w1, bn1, w2b, b2, f2, fg);
  k_fgpart<<<BGT / 16, 256, 0, stream>>>(fg, w3, fgpart);
  k_l34<0><<<NR / 128, 512, L34S_LDS, stream>>>(f2, w3bb, nullptr, fgpart, nullptr, nullptr, partials, nullptr);
  k_bn3<<<8, 1024, 0, stream>>>(partials, g3, be3, bn3);
  k_l34<1><<<NR / 128, 512, L34O_LDS, stream>>>(f2, w3bb, w4b, fgpart, bn3, b4, nullptr, out);
}